// Round 6
// baseline (5646.486 us; speedup 1.0000x reference)
//
#include <hip/hip_runtime.h>
#include <math.h>

// ---------------- constants ----------------
#define SEQ 128
#define BATCH 256
#define INPUT 300
#define HIDDEN 1024
#define NG 4096              // 4*HIDDEN, gate-interleaved: n' = 4*j + gate
#define KH 1024
#define KXP 320              // x K padded 300->320
#define KT 1344              // KH + KXP
#define NKT 42               // KT/32 k-tiles
#define KTH 32               // KH/32 h k-tiles
#define NKTH 32              // head k-tiles (K=1024)
#define LINEARN 1024
#define WROW 1032            // W_hh LDS row stride in shorts (1024 + 8 pad)
#define HBSTEP (1u << 20)    // 1MB per h step buffer: [hi 512K][lo 512K]

typedef __attribute__((ext_vector_type(8))) short short8;
typedef __attribute__((ext_vector_type(4))) float floatx4;

__device__ __forceinline__ float sigf(float x)     { return 1.f / (1.f + __expf(-x)); }
__device__ __forceinline__ float tanhfast(float x) { return 2.f / (1.f + __expf(-2.f * x)) - 1.f; }

__device__ __forceinline__ unsigned short bf16_rne(float f) {
  unsigned u = __float_as_uint(f);
  u += 0x7FFFu + ((u >> 16) & 1u);
  return (unsigned short)(u >> 16);
}
__device__ __forceinline__ float bf16f(unsigned short s) {
  return __uint_as_float(((unsigned)s) << 16);
}

__device__ __forceinline__ void mfma3(floatx4& acc, short8 ah, short8 al, short8 bh, short8 bl) {
  acc = __builtin_amdgcn_mfma_f32_16x16x32_bf16(ah, bh, acc, 0, 0, 0);
  acc = __builtin_amdgcn_mfma_f32_16x16x32_bf16(ah, bl, acc, 0, 0, 0);
  acc = __builtin_amdgcn_mfma_f32_16x16x32_bf16(al, bh, acc, 0, 0, 0);
}
// W kept at bf16 (hi only); A split hi/lo corrects the h/x quantization.
__device__ __forceinline__ void mfma2(floatx4& acc, short8 ah, short8 al, short8 bh) {
  acc = __builtin_amdgcn_mfma_f32_16x16x32_bf16(ah, bh, acc, 0, 0, 0);
  acc = __builtin_amdgcn_mfma_f32_16x16x32_bf16(al, bh, acc, 0, 0, 0);
}

// ---------------- zero ----------------
__global__ __launch_bounds__(256) void zero_ws(float4* p, int n4) {
  int i = blockIdx.x * 256 + threadIdx.x;
  if (i < n4) p[i] = make_float4(0.f, 0.f, 0.f, 0.f);
}

// ---------------- weight pack: gate-interleave + pad, bf16 hi only ----------------
__global__ __launch_bounds__(256) void pack_w(
    const float* __restrict__ W_ih, const float* __restrict__ W_hh,
    unsigned short* __restrict__ Wph)
{
  int id = blockIdx.x * 256 + threadIdx.x;
  if (id >= NG * KT) return;
  int n = id / KT;
  int k = id - n * KT;
  int j = n >> 2, g = n & 3;
  int srow = g * HIDDEN + j;
  float w = 0.f;
  if (k < KH) w = W_hh[(size_t)srow * HIDDEN + k];
  else if (k - KH < INPUT) w = W_ih[(size_t)srow * INPUT + (k - KH)];
  Wph[id] = bf16_rne(w);
}

__global__ __launch_bounds__(256) void pack_bias(
    const float* __restrict__ b_ih, const float* __restrict__ b_hh,
    float* __restrict__ biasp)
{
  int n = blockIdx.x * 256 + threadIdx.x;
  if (n >= NG) return;
  int j = n >> 2, g = n & 3;
  int s = g * HIDDEN + j;
  biasp[n] = b_ih[s] + b_hh[s];
}

// ---------------- pack all x timesteps to bf16 hi/lo, padded 300->320 ----------------
__global__ __launch_bounds__(256) void pack_x(
    const float* __restrict__ x, unsigned short* __restrict__ xph,
    unsigned short* __restrict__ xpl)
{
  int id = blockIdx.x * 256 + threadIdx.x;
  if (id >= SEQ * BATCH * KXP) return;
  int row = id / KXP;
  int k = id - row * KXP;
  float v = (k < INPUT) ? x[(size_t)row * INPUT + k] : 0.f;
  unsigned short hi = bf16_rne(v);
  xph[id] = hi;
  xpl[id] = bf16_rne(v - bf16f(hi));
}

// ---------------- pack W1 (head) hi/lo ----------------
__global__ __launch_bounds__(256) void pack_w1(
    const float* __restrict__ W1, unsigned short* __restrict__ W1ph,
    unsigned short* __restrict__ W1pl)
{
  int id = blockIdx.x * 256 + threadIdx.x;
  if (id >= LINEARN * HIDDEN) return;
  float w = W1[id];
  unsigned short hi = bf16_rne(w);
  W1ph[id] = hi;
  W1pl[id] = bf16_rne(w - bf16f(hi));
}

// x-part for the 512-thread persistent kernel: acc += x[2 row-frags] @ W_ih^T.
// Shares the prefetch register arrays with the h-part (disjoint lifetimes).
__device__ __forceinline__ void xpart512(
    const unsigned short* __restrict__ xh, const unsigned short* __restrict__ xl,
    int rowA, int quad, const short8 (&wx)[10], floatx4 (&acc)[2],
    short8 (&A0)[8], short8 (&A1)[8], short8 (&L0)[8], short8 (&L1)[8])
{
#define LOADX(kx, s) do { const int ko = (kx) * 32 + quad * 8;                \
    A0[s] = *(const short8*)(xh + (size_t)rowA * KXP + ko);                   \
    A1[s] = *(const short8*)(xh + (size_t)(rowA + 16) * KXP + ko);            \
    L0[s] = *(const short8*)(xl + (size_t)rowA * KXP + ko);                   \
    L1[s] = *(const short8*)(xl + (size_t)(rowA + 16) * KXP + ko); } while (0)
#pragma unroll
  for (int v = 0; v < 4; ++v) LOADX(v, v);
#pragma unroll
  for (int kx = 0; kx < 10; ++kx) {
    const int s = kx & 3;
    const short8 a0 = A0[s], a1 = A1[s], l0 = L0[s], l1 = L1[s];
    if (kx + 4 < 10) LOADX(kx + 4, s);
    mfma2(acc[0], a0, l0, wx[kx]);
    mfma2(acc[1], a1, l1, wx[kx]);
  }
#undef LOADX
}

// ---------------- persistent LSTM v3 ----------------
// R5 post-mortem: WRITE_SIZE showed the 8B agent-atomic h-stores write through to
// HBM (serialized at the coherence point) and readers HBM-miss. v3 keeps the
// fresh-address-per-step protocol (R5, verified) but:
//  - h written with PLAIN ushort4 stores (fast, to local L2);
//  - ONE release-agent fence (buffer_wbl2) per block per step flushes them to the
//    coherence point BEFORE the barrier arrive; consumer needs no acquire
//    (addresses never cached in its L1/L2 this launch; runtime WB+INVs at dispatch
//    boundaries between replays — same guarantee the R0 multi-launch path used);
//  - 512 threads / 8 waves (2/SIMD): each wave = 2 m-frags x 1 n-frag -> only 4
//    A-loads per k-tile -> depth-8 prefetch fits VGPRs, halving the load chain;
//  - 1 LDS W-read per k-tile (B shared across the wave's two m-frags).
__global__ __launch_bounds__(512, 2) void lstm_persist3(
    const unsigned short* __restrict__ xph,   // [SEQ*256][320]
    const unsigned short* __restrict__ xpl,
    const unsigned short* __restrict__ Wph,   // [4096][1344] bf16 hi
    const float* __restrict__ biasp,          // [4096]
    char* __restrict__ hbase,                 // 129 x 1MB step buffers
    unsigned int* barcnt)                     // root[mt]=barcnt[mt*32]; sub=barcnt[128+xcd*32]
{
  __shared__ unsigned short wlds[64 * WROW];  // 132096 B
  __shared__ float epi[64 * 65];              // 16640 B

  const int t_   = threadIdx.x;
  const int lane = t_ & 63;
  const int wave = t_ >> 6;                   // 0..7
  const int wm   = (wave >> 2) * 32;          // {0,32}
  const int wn   = (wave & 3) * 16;           // {0,16,32,48}
  const int col  = lane & 15;
  const int quad = lane >> 4;
  const int id   = blockIdx.x;
  const int xcd  = id & 7;
  const int mt_  = xcd >> 1;                  // 2 XCDs per m-tile
  const int jtile = (xcd & 1) * 32 + (id >> 3);
  const int m0 = mt_ * 64, n0 = jtile * 64, j0 = jtile * 16;

  // ---- W_hh tile -> LDS (rows n0..n0+64, k 0..1024), once ----
  for (int i = t_; i < 64 * 128; i += 512) {
    const int row = i >> 7, slot = i & 127;
    *(uint4*)(wlds + row * WROW + slot * 8) =
        *(const uint4*)(Wph + (size_t)(n0 + row) * KT + slot * 8);
  }
  // ---- W_ih frag -> regs (10 k-tiles x 1 n-frag = 40 VGPRs), once ----
  short8 wx[10];
#pragma unroll
  for (int kx = 0; kx < 10; ++kx)
    wx[kx] = *(const short8*)(Wph + (size_t)(n0 + wn + col) * KT + KH + kx * 32 + quad * 8);

  const float bias0 = biasp[n0 + wn + col];

  // epilogue mapping fixed across steps -> cell state lives in these 4 regs (t_<256)
  const int mloc = t_ >> 2;
  const int jl4  = (t_ & 3) * 4;
  float c4[4] = {0.f, 0.f, 0.f, 0.f};

  const int rowA = m0 + wm + col;
  const unsigned short* wrow = wlds + (wn + col) * WROW + quad * 8;

  __syncthreads();

  floatx4 acc[2];
  short8 A0[8], A1[8], L0[8], L1[8];          // prefetch slots, shared x/h parts

  acc[0] = (floatx4){0.f, 0.f, 0.f, 0.f};
  acc[1] = (floatx4){0.f, 0.f, 0.f, 0.f};
  // prologue: x-part for step 0 (h[0]=0 -> acc starts as the x contribution)
  xpart512(xph, xpl, rowA, quad, wx, acc, A0, A1, L0, L1);

#pragma unroll 1
  for (int st = 0; st < SEQ; ++st) {
    // ---- wait for h[st] (mt-local barrier; skip st=0: h[0] pre-zeroed) ----
    if (st > 0) {
      if (t_ == 0) {
        const unsigned tgt = (unsigned)(st * 2);
        while (__hip_atomic_load(barcnt + mt_ * 32, __ATOMIC_RELAXED,
                                 __HIP_MEMORY_SCOPE_AGENT) < tgt)
          __builtin_amdgcn_s_sleep(1);
      }
      __syncthreads();
    }

    const unsigned short* hrh = (const unsigned short*)(hbase + (size_t)st * HBSTEP);
    const unsigned short* hrl = hrh + 262144;

    // ---- h-part: 32 k-tiles, plain cached loads (fresh addrs), depth-8 ----
#define LOADH(kt, s) do { const int ko = (kt) * 32 + quad * 8;                \
      A0[s] = *(const short8*)(hrh + (size_t)rowA * KH + ko);                 \
      A1[s] = *(const short8*)(hrh + (size_t)(rowA + 16) * KH + ko);          \
      L0[s] = *(const short8*)(hrl + (size_t)rowA * KH + ko);                 \
      L1[s] = *(const short8*)(hrl + (size_t)(rowA + 16) * KH + ko); } while (0)
#pragma unroll
    for (int v = 0; v < 8; ++v) LOADH(v, v);
#pragma unroll
    for (int kt = 0; kt < KTH; ++kt) {
      const int s = kt & 7;
      const short8 bh = *(const short8*)(wrow + kt * 32);
      const short8 a0 = A0[s], a1 = A1[s], l0 = L0[s], l1 = L1[s];
      if (kt + 8 < KTH) LOADH(kt + 8, s);
      mfma2(acc[0], a0, l0, bh);
      mfma2(acc[1], a1, l1, bh);
    }
#undef LOADH

    // ---- epilogue: gates -> epi[n'][m] (+bias), fused cell update ----
#pragma unroll
    for (int mt = 0; mt < 2; ++mt) {
      const int nl = wn + col;
#pragma unroll
      for (int reg = 0; reg < 4; ++reg) {
        const int ml = wm + mt * 16 + quad * 4 + reg;
        epi[nl * 65 + ml] = acc[mt][reg] + bias0;
      }
    }
    __syncthreads();

    unsigned short* hwh = (unsigned short*)(hbase + (size_t)(st + 1) * HBSTEP);
    unsigned short* hwl = hwh + 262144;
    if (t_ < 256) {
      float hn[4];
#pragma unroll
      for (int jj = 0; jj < 4; ++jj) {
        const int nl = (jl4 + jj) * 4;
        const float gi = epi[(nl + 0) * 65 + mloc];
        const float gf = epi[(nl + 1) * 65 + mloc];
        const float gg = epi[(nl + 2) * 65 + mloc];
        const float go = epi[(nl + 3) * 65 + mloc];
        const float cnew = sigf(gf) * c4[jj] + sigf(gi) * tanhfast(gg);
        c4[jj] = cnew;
        hn[jj] = sigf(go) * tanhfast(cnew);
      }
      ushort4 uh, ul;
      uh.x = bf16_rne(hn[0]); uh.y = bf16_rne(hn[1]);
      uh.z = bf16_rne(hn[2]); uh.w = bf16_rne(hn[3]);
      ul.x = bf16_rne(hn[0] - bf16f(uh.x));
      ul.y = bf16_rne(hn[1] - bf16f(uh.y));
      ul.z = bf16_rne(hn[2] - bf16f(uh.z));
      ul.w = bf16_rne(hn[3] - bf16f(uh.w));
      // PLAIN stores -> local L2 (fast); made visible by the release fence below.
      *(ushort4*)(hwh + (size_t)(m0 + mloc) * KH + (j0 + jl4)) = uh;
      *(ushort4*)(hwl + (size_t)(m0 + mloc) * KH + (j0 + jl4)) = ul;
    }

    __syncthreads();   // per-wave vmcnt(0) drain: all h stores resident in L2
    if (t_ == 0) {
      // release: write back this XCD's L2 to the coherence point (no invalidate),
      // then arrive. Consumer needs no acquire: h[st+1] addrs are fresh to it.
      __builtin_amdgcn_fence(__ATOMIC_RELEASE, "agent");
      unsigned* gc = barcnt + 128 + xcd * 32;
      const unsigned old =
          __hip_atomic_fetch_add(gc, 1u, __ATOMIC_RELAXED, __HIP_MEMORY_SCOPE_AGENT);
      if (old == (unsigned)(st * 32 + 31))
        __hip_atomic_fetch_add(barcnt + mt_ * 32, 1u, __ATOMIC_RELAXED,
                               __HIP_MEMORY_SCOPE_AGENT);
    }
    // ---- x-part for st+1 (no h dependency): hides barrier propagation ----
    if (st + 1 < SEQ) {
      acc[0] = (floatx4){0.f, 0.f, 0.f, 0.f};
      acc[1] = (floatx4){0.f, 0.f, 0.f, 0.f};
      xpart512(xph + (size_t)(st + 1) * BATCH * KXP,
               xpl + (size_t)(st + 1) * BATCH * KXP,
               rowA, quad, wx, acc, A0, A1, L0, L1);
    }
  }
}

// ---------------- OLD per-step kernel (fallback when workspace too small) ----------------
__global__ __launch_bounds__(256) void lstm_step(
    const unsigned short* __restrict__ xp_hi, const unsigned short* __restrict__ xp_lo,
    const unsigned short* __restrict__ h_hi_r, const unsigned short* __restrict__ h_lo_r,
    const unsigned short* __restrict__ Wph, const float* __restrict__ biasp,
    float* __restrict__ cst, unsigned short* __restrict__ h_hi_w,
    unsigned short* __restrict__ h_lo_w)
{
  __shared__ short sb[2 * 7680];
  const int t    = threadIdx.x;
  const int lane = t & 63;
  const int wave = t >> 6;
  const int wm   = (wave >> 1) * 32;
  const int wn   = (wave & 1) * 32;
  const int col  = lane & 15;
  const int quad = lane >> 4;
  const int r    = t >> 2;
  const int k8   = (t & 3) * 8;
  const int id     = blockIdx.x;
  const int jtile  = (id & 7) * 8 + ((id >> 3) & 7);
  const int mt_    = id >> 6;
  const int m0   = mt_ * 64;
  const int n0   = jtile * 64;
  const int j0   = jtile * 16;

#define LOAD_TILE(kt, AH, AL, BH) do {                                       \
    if ((kt) < KTH) {                                                        \
      const int ka = (kt) * 32 + k8;                                         \
      AH = *(const uint4*)(h_hi_r + (size_t)(m0 + r) * KH + ka);             \
      AL = *(const uint4*)(h_lo_r + (size_t)(m0 + r) * KH + ka);             \
    } else {                                                                 \
      const int kx = ((kt) - KTH) * 32 + k8;                                 \
      AH = *(const uint4*)(xp_hi + (size_t)(m0 + r) * KXP + kx);             \
      AL = *(const uint4*)(xp_lo + (size_t)(m0 + r) * KXP + kx);             \
    }                                                                        \
    BH = *(const uint4*)(Wph + (size_t)(n0 + r) * KT + (kt) * 32 + k8);      \
  } while (0)
#define STORE_TILE(base, AH, AL, BH) do {                                    \
    *(uint4*)((base) +        r * 40 + k8) = AH;                             \
    *(uint4*)((base) + 2560 + r * 40 + k8) = AL;                             \
    *(uint4*)((base) + 5120 + r * 40 + k8) = BH;                             \
  } while (0)

  floatx4 acc[2][2];
#pragma unroll
  for (int i = 0; i < 2; ++i)
#pragma unroll
    for (int jj = 0; jj < 2; ++jj)
      acc[i][jj] = (floatx4){0.f, 0.f, 0.f, 0.f};

  uint4 cAh, cAl, cBh, nAh, nAl, nBh, tAh, tAl, tBh;
  LOAD_TILE(0, tAh, tAl, tBh);
  LOAD_TILE(1, cAh, cAl, cBh);
  STORE_TILE(sb, tAh, tAl, tBh);

  for (int kt = 0; kt < NKT; ++kt) {
    if (kt + 2 < NKT) LOAD_TILE(kt + 2, nAh, nAl, nBh);
    __syncthreads();
    short* bufp = sb + (kt & 1) * 7680;
    short8 ah[2], al[2], bh[2];
#pragma unroll
    for (int mt = 0; mt < 2; ++mt) {
      const int row = (wm + mt * 16 + col) * 40 + quad * 8;
      ah[mt] = *(const short8*)(bufp + row);
      al[mt] = *(const short8*)(bufp + 2560 + row);
    }
#pragma unroll
    for (int nt = 0; nt < 2; ++nt) {
      const int row = (wn + nt * 16 + col) * 40 + quad * 8;
      bh[nt] = *(const short8*)(bufp + 5120 + row);
    }
#pragma unroll
    for (int mt = 0; mt < 2; ++mt)
#pragma unroll
      for (int nt = 0; nt < 2; ++nt)
        mfma2(acc[mt][nt], ah[mt], al[mt], bh[nt]);
    if (kt + 1 < NKT) STORE_TILE(sb + ((kt + 1) & 1) * 7680, cAh, cAl, cBh);
    cAh = nAh; cAl = nAl; cBh = nBh;
  }
#undef LOAD_TILE
#undef STORE_TILE

  __syncthreads();
  float* epi = (float*)sb;
#pragma unroll
  for (int mt = 0; mt < 2; ++mt)
#pragma unroll
    for (int nt = 0; nt < 2; ++nt) {
      const int nl = wn + nt * 16 + col;
      const float bb = biasp[n0 + nl];
#pragma unroll
      for (int reg = 0; reg < 4; ++reg) {
        const int ml = wm + mt * 16 + quad * 4 + reg;
        epi[nl * 65 + ml] = acc[mt][nt][reg] + bb;
      }
    }
  __syncthreads();

  const int mloc = t >> 2;
  const int jl4  = (t & 3) * 4;
  const int m    = m0 + mloc;
  const int j    = j0 + jl4;
  float4 cold = *(const float4*)(cst + (size_t)m * HIDDEN + j);
  float cn[4], hn[4];
#pragma unroll
  for (int jj = 0; jj < 4; ++jj) {
    const int nl = (jl4 + jj) * 4;
    const float gi = epi[(nl + 0) * 65 + mloc];
    const float gf = epi[(nl + 1) * 65 + mloc];
    const float gg = epi[(nl + 2) * 65 + mloc];
    const float go = epi[(nl + 3) * 65 + mloc];
    const float cc = (jj == 0) ? cold.x : (jj == 1) ? cold.y : (jj == 2) ? cold.z : cold.w;
    const float cnew = sigf(gf) * cc + sigf(gi) * tanhfast(gg);
    cn[jj] = cnew;
    hn[jj] = sigf(go) * tanhfast(cnew);
  }
  *(float4*)(cst + (size_t)m * HIDDEN + j) = make_float4(cn[0], cn[1], cn[2], cn[3]);
  ushort4 uh, ul;
  uh.x = bf16_rne(hn[0]); uh.y = bf16_rne(hn[1]); uh.z = bf16_rne(hn[2]); uh.w = bf16_rne(hn[3]);
  ul.x = bf16_rne(hn[0] - bf16f(uh.x));
  ul.y = bf16_rne(hn[1] - bf16f(uh.y));
  ul.z = bf16_rne(hn[2] - bf16f(uh.z));
  ul.w = bf16_rne(hn[3] - bf16f(uh.w));
  *(ushort4*)(h_hi_w + (size_t)m * HIDDEN + j) = uh;
  *(ushort4*)(h_lo_w + (size_t)m * HIDDEN + j) = ul;
}

// ---------------- head GEMM: z = h @ W1^T + b1 (64x64 LDS pipelined, 3-MFMA) ----------------
__global__ __launch_bounds__(256) void head_gemm(
    const unsigned short* __restrict__ Ah_,     // h_hi [256][1024]
    const unsigned short* __restrict__ Al_,
    const unsigned short* __restrict__ Bh_,     // W1 hi [1024][1024]
    const unsigned short* __restrict__ Bl_,
    const float* __restrict__ bias,
    float* __restrict__ C)                      // z [256][1024]
{
  __shared__ short sb[2 * 4 * 2560];

  const int t    = threadIdx.x;
  const int lane = t & 63;
  const int wave = t >> 6;
  const int wm   = (wave >> 1) * 32;
  const int wn   = (wave & 1) * 32;
  const int col  = lane & 15;
  const int quad = lane >> 4;
  const int r    = t >> 2;
  const int k8   = (t & 3) * 8;
  const int m0   = blockIdx.y * 64;
  const int n0   = blockIdx.x * 64;

#define LOAD_TILE(kt, AH, AL, BH, BL) do {                                   \
    const int ka = (kt) * 32 + k8;                                           \
    AH = *(const uint4*)(Ah_ + (size_t)(m0 + r) * KH + ka);                  \
    AL = *(const uint4*)(Al_ + (size_t)(m0 + r) * KH + ka);                  \
    BH = *(const uint4*)(Bh_ + (size_t)(n0 + r) * KH + ka);                  \
    BL = *(const uint4*)(Bl_ + (size_t)(n0 + r) * KH + ka);                  \
  } while (0)

#define STORE_TILE(base, AH, AL, BH, BL) do {                                \
    *(uint4*)((base) +        r * 40 + k8) = AH;                             \
    *(uint4*)((base) + 2560 + r * 40 + k8) = AL;                             \
    *(uint4*)((base) + 5120 + r * 40 + k8) = BH;                             \
    *(uint4*)((base) + 7680 + r * 40 + k8) = BL;                             \
  } while (0)

  floatx4 acc[2][2];
#pragma unroll
  for (int i = 0; i < 2; ++i)
#pragma unroll
    for (int jj = 0; jj < 2; ++jj)
      acc[i][jj] = (floatx4){0.f, 0.f, 0.f, 0.f};

  uint4 cAh, cAl, cBh, cBl, nAh, nAl, nBh, nBl, tAh, tAl, tBh, tBl;
  LOAD_TILE(0, tAh, tAl, tBh, tBl);
  LOAD_TILE(1, cAh, cAl, cBh, cBl);
  STORE_TILE(sb, tAh, tAl, tBh, tBl);

  for (int kt = 0; kt < NKTH; ++kt) {
    if (kt + 2 < NKTH) LOAD_TILE(kt + 2, nAh, nAl, nBh, nBl);
    __syncthreads();
    short* bufp = sb + (kt & 1) * 10240;

    short8 ah[2], al[2], bh[2], bl[2];
#pragma unroll
    for (int mt = 0; mt < 2; ++mt) {
      const int row = (wm + mt * 16 + col) * 40 + quad * 8;
      ah[mt] = *(const short8*)(bufp + row);
      al[mt] = *(const short8*)(bufp + 2560 + row);
    }
#pragma unroll
    for (int nt = 0; nt < 2; ++nt) {
      const int row = (wn + nt * 16 + col) * 40 + quad * 8;
      bh[nt] = *(const short8*)(bufp + 5120 + row);
      bl[nt] = *(const short8*)(bufp + 7680 + row);
    }
#pragma unroll
    for (int mt = 0; mt < 2; ++mt)
#pragma unroll
      for (int nt = 0; nt < 2; ++nt)
        mfma3(acc[mt][nt], ah[mt], al[mt], bh[nt], bl[nt]);

    if (kt + 1 < NKTH) STORE_TILE(sb + ((kt + 1) & 1) * 10240, cAh, cAl, cBh, cBl);
    cAh = nAh; cAl = nAl; cBh = nBh; cBl = nBl;
  }
#undef LOAD_TILE
#undef STORE_TILE

#pragma unroll
  for (int mt = 0; mt < 2; ++mt)
#pragma unroll
    for (int nt = 0; nt < 2; ++nt) {
      const int nl = n0 + wn + nt * 16 + col;
      const float bb = bias[nl];
#pragma unroll
      for (int reg = 0; reg < 4; ++reg) {
        const int ml = m0 + wm + mt * 16 + quad * 4 + reg;
        C[(size_t)ml * LINEARN + nl] = acc[mt][nt][reg] + bb;
      }
    }
}

// ---------------- BN stats ----------------
__global__ __launch_bounds__(64) void bn_stats(
    const float* __restrict__ z, float* __restrict__ mean, float* __restrict__ rstd)
{
  const int n = blockIdx.x;
  const int t = threadIdx.x;
  float s = 0.f, s2 = 0.f;
  for (int r = t; r < BATCH; r += 64) {
    const float v = z[(size_t)r * LINEARN + n];
    s += v; s2 += v * v;
  }
#pragma unroll
  for (int off = 32; off > 0; off >>= 1) {
    s  += __shfl_down(s,  off, 64);
    s2 += __shfl_down(s2, off, 64);
  }
  if (t == 0) {
    const float mm = s * (1.f / BATCH);
    mean[n] = mm;
    rstd[n] = rsqrtf(s2 * (1.f / BATCH) - mm * mm + 1e-5f);
  }
}

// ---------------- head out ----------------
__global__ __launch_bounds__(256) void head_out(
    const float* __restrict__ z, const float* __restrict__ mean, const float* __restrict__ rstd,
    const float* __restrict__ gamma, const float* __restrict__ beta,
    const float* __restrict__ W2, const float* __restrict__ b2, float* __restrict__ out)
{
  const int b = blockIdx.x;
  const int t = threadIdx.x;
  float acc = 0.f;
  for (int n = t; n < LINEARN; n += 256) {
    float v = (z[(size_t)b * LINEARN + n] - mean[n]) * rstd[n] * gamma[n] + beta[n];
    v = fmaxf(v, 0.f);
    acc += v * W2[n];
  }
#pragma unroll
  for (int off = 32; off > 0; off >>= 1) acc += __shfl_down(acc, off, 64);
  __shared__ float ls[4];
  if ((t & 63) == 0) ls[t >> 6] = acc;
  __syncthreads();
  if (t == 0) {
    const float tot = ls[0] + ls[1] + ls[2] + ls[3] + b2[0];
    out[b] = 3.f / (1.f + __expf(-tot));
  }
}

// ---------------- launch ----------------
extern "C" void kernel_launch(void* const* d_in, const int* in_sizes, int n_in,
                              void* d_out, int out_size, void* d_ws, size_t ws_size,
                              hipStream_t stream) {
  const float* x     = (const float*)d_in[0];
  const float* W_ih  = (const float*)d_in[1];
  const float* W_hh  = (const float*)d_in[2];
  const float* b_ih  = (const float*)d_in[3];
  const float* b_hh  = (const float*)d_in[4];
  const float* W1    = (const float*)d_in[5];
  const float* b1    = (const float*)d_in[6];
  const float* gamma = (const float*)d_in[7];
  const float* beta  = (const float*)d_in[8];
  const float* W2    = (const float*)d_in[9];
  const float* b2    = (const float*)d_in[10];
  float* out = (float*)d_out;
  char* w = (char*)d_ws;

  // new-path layout
  const size_t HB_OFF   = 0;                     // 129 x 1MB = 135,266,304
  const size_t BARC_OFF = 135266304;             // 4 KB
  const size_t WPH_OFF  = 135270400;             // 11,010,048
  const size_t BIAS_OFF = 146280448;             // 16 KB
  const size_t XPH_OFF  = 146296832;             // 20,971,520
  const size_t XPL_OFF  = 167268352;             // 20,971,520
  const size_t W1PH_OFF = 188239872;             // 2 MB
  const size_t W1PL_OFF = 190337024;             // 2 MB
  const size_t Z_OFF    = 192434176;             // 1 MB
  const size_t MEAN_OFF = 193482752;
  const size_t RSTD_OFF = 193486848;
  const size_t NEED     = 193490944;

  if (ws_size >= NEED) {
    unsigned short* Wph   = (unsigned short*)(w + WPH_OFF);
    float*          biasp = (float*)(w + BIAS_OFF);
    unsigned short* xph   = (unsigned short*)(w + XPH_OFF);
    unsigned short* xpl   = (unsigned short*)(w + XPL_OFF);
    unsigned short* W1ph  = (unsigned short*)(w + W1PH_OFF);
    unsigned short* W1pl  = (unsigned short*)(w + W1PL_OFF);
    float*          z     = (float*)(w + Z_OFF);
    float*          mean  = (float*)(w + MEAN_OFF);
    float*          rstd  = (float*)(w + RSTD_OFF);

    zero_ws<<<256, 256, 0, stream>>>((float4*)(w + HB_OFF), 65536);      // h[0] = 0
    zero_ws<<<1, 256, 0, stream>>>((float4*)(w + BARC_OFF), 256);        // barrier counters
    pack_w<<<(NG * KT + 255) / 256, 256, 0, stream>>>(W_ih, W_hh, Wph);
    pack_bias<<<NG / 256, 256, 0, stream>>>(b_ih, b_hh, biasp);
    pack_x<<<(SEQ * BATCH * KXP + 255) / 256, 256, 0, stream>>>(x, xph, xpl);
    pack_w1<<<(LINEARN * HIDDEN + 255) / 256, 256, 0, stream>>>(W1, W1ph, W1pl);

    lstm_persist3<<<256, 512, 0, stream>>>(
        xph, xpl, Wph, biasp, w + HB_OFF, (unsigned int*)(w + BARC_OFF));

    const unsigned short* hfh = (const unsigned short*)(w + HB_OFF + (size_t)SEQ * HBSTEP);
    const unsigned short* hfl = hfh + 262144;
    head_gemm<<<dim3(LINEARN / 64, BATCH / 64), 256, 0, stream>>>(
        hfh, hfl, W1ph, W1pl, b1, z);
    bn_stats<<<LINEARN, 64, 0, stream>>>(z, mean, rstd);
    head_out<<<BATCH, 256, 0, stream>>>(z, mean, rstd, gamma, beta, W2, b2, out);
  } else {
    // -------- fallback: verified 128-launch path (R0 layout) --------
    unsigned short* h_hi0 = (unsigned short*)(w + 0);
    unsigned short* h_lo0 = (unsigned short*)(w + 524288);
    float*          cst   = (float*)(w + 1048576);
    unsigned short* h_hi1 = (unsigned short*)(w + 2097152);
    unsigned short* h_lo1 = (unsigned short*)(w + 2621440);
    unsigned short* Wph   = (unsigned short*)(w + 3145728);
    float*          biasp = (float*)(w + 14155776);
    unsigned short* xph   = (unsigned short*)(w + 14172160);
    unsigned short* xpl   = (unsigned short*)(w + 35143680);
    unsigned short* W1ph  = (unsigned short*)(w + 56115200);
    unsigned short* W1pl  = (unsigned short*)(w + 58212352);
    float*          z     = (float*)(w + 60309504);
    float*          mean  = (float*)(w + 61358080);
    float*          rstd  = (float*)(w + 61362176);

    zero_ws<<<512, 256, 0, stream>>>((float4*)w, 131072);
    pack_w<<<(NG * KT + 255) / 256, 256, 0, stream>>>(W_ih, W_hh, Wph);
    pack_bias<<<NG / 256, 256, 0, stream>>>(b_ih, b_hh, biasp);
    pack_x<<<(SEQ * BATCH * KXP + 255) / 256, 256, 0, stream>>>(x, xph, xpl);
    pack_w1<<<(LINEARN * HIDDEN + 255) / 256, 256, 0, stream>>>(W1, W1ph, W1pl);

    for (int t = 0; t < SEQ; ++t) {
      const unsigned short* hr_hi = (t & 1) ? h_hi1 : h_hi0;
      const unsigned short* hr_lo = (t & 1) ? h_lo1 : h_lo0;
      unsigned short* hw_hi = (t & 1) ? h_hi0 : h_hi1;
      unsigned short* hw_lo = (t & 1) ? h_lo0 : h_lo1;
      lstm_step<<<256, 256, 0, stream>>>(
          xph + (size_t)t * BATCH * KXP, xpl + (size_t)t * BATCH * KXP,
          hr_hi, hr_lo, Wph, biasp, cst, hw_hi, hw_lo);
    }
    head_gemm<<<dim3(LINEARN / 64, BATCH / 64), 256, 0, stream>>>(
        h_hi0, h_lo0, W1ph, W1pl, b1, z);
    bn_stats<<<LINEARN, 64, 0, stream>>>(z, mean, rstd);
    head_out<<<BATCH, 256, 0, stream>>>(z, mean, rstd, gamma, beta, W2, b2, out);
  }
}

// Round 7
// 3916.542 us; speedup vs baseline: 1.4417x; 1.4417x over previous
//
#include <hip/hip_runtime.h>
#include <math.h>

// ---------------- constants ----------------
#define SEQ 128
#define BATCH 256
#define INPUT 300
#define HIDDEN 1024
#define NG 4096              // 4*HIDDEN, gate-interleaved: n' = 4*j + gate
#define KH 1024
#define KXP 320              // x K padded 300->320
#define KT 1344              // KH + KXP
#define KTH 32               // KH/32 h k-tiles
#define NKTH 32              // head k-tiles (K=1024)
#define LINEARN 1024
#define WROW 1032            // W_hh LDS row stride in shorts (1024 + 8 pad)

typedef __attribute__((ext_vector_type(8))) short short8;
typedef __attribute__((ext_vector_type(4))) float floatx4;

__device__ __forceinline__ float sigf(float x)     { return 1.f / (1.f + __expf(-x)); }
__device__ __forceinline__ float tanhfast(float x) { return 2.f / (1.f + __expf(-2.f * x)) - 1.f; }

__device__ __forceinline__ unsigned short bf16_rne(float f) {
  unsigned u = __float_as_uint(f);
  u += 0x7FFFu + ((u >> 16) & 1u);
  return (unsigned short)(u >> 16);
}
__device__ __forceinline__ float bf16f(unsigned short s) {
  return __uint_as_float(((unsigned)s) << 16);
}

__device__ __forceinline__ void mfma3(floatx4& acc, short8 ah, short8 al, short8 bh, short8 bl) {
  acc = __builtin_amdgcn_mfma_f32_16x16x32_bf16(ah, bh, acc, 0, 0, 0);
  acc = __builtin_amdgcn_mfma_f32_16x16x32_bf16(ah, bl, acc, 0, 0, 0);
  acc = __builtin_amdgcn_mfma_f32_16x16x32_bf16(al, bh, acc, 0, 0, 0);
}
// W kept at bf16 (hi only); A split hi/lo corrects the h/x quantization.
__device__ __forceinline__ void mfma2(floatx4& acc, short8 ah, short8 al, short8 bh) {
  acc = __builtin_amdgcn_mfma_f32_16x16x32_bf16(ah, bh, acc, 0, 0, 0);
  acc = __builtin_amdgcn_mfma_f32_16x16x32_bf16(al, bh, acc, 0, 0, 0);
}

// ---------------- zero ----------------
__global__ __launch_bounds__(256) void zero_ws(float4* p, int n4) {
  int i = blockIdx.x * 256 + threadIdx.x;
  if (i < n4) p[i] = make_float4(0.f, 0.f, 0.f, 0.f);
}

// ---------------- weight pack: gate-interleave + pad, bf16 hi only ----------------
__global__ __launch_bounds__(256) void pack_w(
    const float* __restrict__ W_ih, const float* __restrict__ W_hh,
    unsigned short* __restrict__ Wph)
{
  int id = blockIdx.x * 256 + threadIdx.x;
  if (id >= NG * KT) return;
  int n = id / KT;
  int k = id - n * KT;
  int j = n >> 2, g = n & 3;
  int srow = g * HIDDEN + j;
  float w = 0.f;
  if (k < KH) w = W_hh[(size_t)srow * HIDDEN + k];
  else if (k - KH < INPUT) w = W_ih[(size_t)srow * INPUT + (k - KH)];
  Wph[id] = bf16_rne(w);
}

__global__ __launch_bounds__(256) void pack_bias(
    const float* __restrict__ b_ih, const float* __restrict__ b_hh,
    float* __restrict__ biasp)
{
  int n = blockIdx.x * 256 + threadIdx.x;
  if (n >= NG) return;
  int j = n >> 2, g = n & 3;
  int s = g * HIDDEN + j;
  biasp[n] = b_ih[s] + b_hh[s];
}

// ---------------- pack all x timesteps to bf16 hi/lo, padded 300->320 ----------------
__global__ __launch_bounds__(256) void pack_x(
    const float* __restrict__ x, unsigned short* __restrict__ xph,
    unsigned short* __restrict__ xpl)
{
  int id = blockIdx.x * 256 + threadIdx.x;
  if (id >= SEQ * BATCH * KXP) return;
  int row = id / KXP;
  int k = id - row * KXP;
  float v = (k < INPUT) ? x[(size_t)row * INPUT + k] : 0.f;
  unsigned short hi = bf16_rne(v);
  xph[id] = hi;
  xpl[id] = bf16_rne(v - bf16f(hi));
}

// ---------------- pack W1 (head) hi/lo ----------------
__global__ __launch_bounds__(256) void pack_w1(
    const float* __restrict__ W1, unsigned short* __restrict__ W1ph,
    unsigned short* __restrict__ W1pl)
{
  int id = blockIdx.x * 256 + threadIdx.x;
  if (id >= LINEARN * HIDDEN) return;
  float w = W1[id];
  unsigned short hi = bf16_rne(w);
  W1ph[id] = hi;
  W1pl[id] = bf16_rne(w - bf16f(hi));
}

// ---------------- per-step LSTM v4: LDS-resident W, barrier-light, HW dispatch sync ----
// R6 lesson: software device barriers cost ~18us/step (serialized agent RMWs + polls);
// the HW dispatch boundary does the same sync in ~3-4us. So: keep 128 launches, but
// replace R0's 42x(2-barrier LDS-staged) body with the R5 persistent body:
//   - W_hh 64x1024 tile -> LDS once per launch (R0 XCD swizzle: 4 same-jtile blocks
//     share one XCD's L2 -> W pulled from L3 once, ~11MB/step device-wide);
//   - W_ih tile in 80 VGPRs; bias in 2 VGPRs; cst prefetched before the K-loop;
//   - A (h,x hi/lo) direct-from-global, depth-4 register prefetch (VGPR ~132, no
//     spill -- R6's depth-8 spilled at VGPR 88 and regressed 2x);
//   - 2 __syncthreads per step (W-fill publish, epilogue transpose) vs R0's 84.
__global__ __launch_bounds__(256, 1) void lstm_step4(
    const unsigned short* __restrict__ xp_hi,   // [256][320] this step
    const unsigned short* __restrict__ xp_lo,
    const unsigned short* __restrict__ h_hi_r,  // [256][1024]
    const unsigned short* __restrict__ h_lo_r,
    const unsigned short* __restrict__ Wph,     // [4096][1344] bf16 hi
    const float* __restrict__ biasp,            // [4096]
    float* __restrict__ cst,                    // [256][1024] fp32 cell state
    unsigned short* __restrict__ h_hi_w,
    unsigned short* __restrict__ h_lo_w)
{
  __shared__ unsigned short wlds[64 * WROW];  // 132096 B
  __shared__ float epi[64 * 65];              // 16640 B

  const int t_   = threadIdx.x;
  const int lane = t_ & 63;
  const int wave = t_ >> 6;
  const int wm   = (wave >> 1) * 32;
  const int wn   = (wave & 1) * 32;
  const int col  = lane & 15;
  const int quad = lane >> 4;
  const int id    = blockIdx.x;
  const int jtile = (id & 7) * 8 + ((id >> 3) & 7);   // XCD-local j grouping (W L2-shared)
  const int mt_   = id >> 6;
  const int m0 = mt_ * 64, n0 = jtile * 64, j0 = jtile * 16;

  // epilogue mapping (fixed): this thread owns c/h rows m0+mloc, cols j0+jl4..+4
  const int mloc = t_ >> 2;
  const int jl4  = (t_ & 3) * 4;

  // ---- cst prefetch (L3 latency hides under W fill + K loop) ----
  const float4 cold = *(const float4*)(cst + (size_t)(m0 + mloc) * HIDDEN + (j0 + jl4));

  // ---- W_ih tile -> regs (10 k-tiles x 2 n-frags = 80 VGPRs) ----
  short8 wx[10][2];
#pragma unroll
  for (int kx = 0; kx < 10; ++kx)
#pragma unroll
    for (int nt = 0; nt < 2; ++nt)
      wx[kx][nt] = *(const short8*)(Wph + (size_t)(n0 + wn + nt * 16 + col) * KT
                                    + KH + kx * 32 + quad * 8);

  // ---- W_hh tile -> LDS (rows n0..n0+64, k 0..1024) ----
  for (int i = t_; i < 64 * 128; i += 256) {
    const int row = i >> 7, slot = i & 127;
    *(uint4*)(wlds + row * WROW + slot * 8) =
        *(const uint4*)(Wph + (size_t)(n0 + row) * KT + slot * 8);
  }

  const float bias0 = biasp[n0 + wn + col];
  const float bias1 = biasp[n0 + wn + 16 + col];

  const int rowA = m0 + wm + col;
  const unsigned short* wrow = wlds + (wn + col) * WROW + quad * 8;

  __syncthreads();   // publish wlds

  floatx4 acc[2][2];
#pragma unroll
  for (int i = 0; i < 2; ++i)
#pragma unroll
    for (int j = 0; j < 2; ++j) acc[i][j] = (floatx4){0.f, 0.f, 0.f, 0.f};

  short8 A0[4], A1[4], L0[4], L1[4];   // depth-4 prefetch slots (shared x/h phases)

  // ---- x-part: 10 k-tiles, W in regs ----
#define LOADX(kx, s) do { const int ko = (kx) * 32 + quad * 8;                \
    A0[s] = *(const short8*)(xp_hi + (size_t)rowA * KXP + ko);                \
    A1[s] = *(const short8*)(xp_hi + (size_t)(rowA + 16) * KXP + ko);         \
    L0[s] = *(const short8*)(xp_lo + (size_t)rowA * KXP + ko);                \
    L1[s] = *(const short8*)(xp_lo + (size_t)(rowA + 16) * KXP + ko); } while (0)
#pragma unroll
  for (int v = 0; v < 4; ++v) LOADX(v, v);
#pragma unroll
  for (int kx = 0; kx < 10; ++kx) {
    const int s = kx & 3;
    const short8 a0 = A0[s], a1 = A1[s], l0 = L0[s], l1 = L1[s];
    if (kx + 4 < 10) LOADX(kx + 4, s);
    mfma2(acc[0][0], a0, l0, wx[kx][0]);
    mfma2(acc[0][1], a0, l0, wx[kx][1]);
    mfma2(acc[1][0], a1, l1, wx[kx][0]);
    mfma2(acc[1][1], a1, l1, wx[kx][1]);
  }
#undef LOADX

  // ---- h-part: 32 k-tiles, W from LDS, A direct-from-global depth-4 ----
#define LOADH(kt, s) do { const int ko = (kt) * 32 + quad * 8;                \
    A0[s] = *(const short8*)(h_hi_r + (size_t)rowA * KH + ko);                \
    A1[s] = *(const short8*)(h_hi_r + (size_t)(rowA + 16) * KH + ko);         \
    L0[s] = *(const short8*)(h_lo_r + (size_t)rowA * KH + ko);                \
    L1[s] = *(const short8*)(h_lo_r + (size_t)(rowA + 16) * KH + ko); } while (0)
#pragma unroll
  for (int v = 0; v < 4; ++v) LOADH(v, v);
#pragma unroll
  for (int kt = 0; kt < KTH; ++kt) {
    const int s = kt & 3;
    const short8 bh0 = *(const short8*)(wrow + kt * 32);
    const short8 bh1 = *(const short8*)(wrow + 16 * WROW + kt * 32);
    const short8 a0 = A0[s], a1 = A1[s], l0 = L0[s], l1 = L1[s];
    if (kt + 4 < KTH) LOADH(kt + 4, s);
    mfma2(acc[0][0], a0, l0, bh0);
    mfma2(acc[0][1], a0, l0, bh1);
    mfma2(acc[1][0], a1, l1, bh0);
    mfma2(acc[1][1], a1, l1, bh1);
  }
#undef LOADH

  // ---- epilogue: gates -> epi[n'][m] (+bias), fused cell update ----
#pragma unroll
  for (int mt = 0; mt < 2; ++mt)
#pragma unroll
    for (int nt = 0; nt < 2; ++nt) {
      const int nl = wn + nt * 16 + col;
      const float bb = nt ? bias1 : bias0;
#pragma unroll
      for (int reg = 0; reg < 4; ++reg) {
        const int ml = wm + mt * 16 + quad * 4 + reg;
        epi[nl * 65 + ml] = acc[mt][nt][reg] + bb;
      }
    }
  __syncthreads();

  float cn[4], hn[4];
#pragma unroll
  for (int jj = 0; jj < 4; ++jj) {
    const int nl = (jl4 + jj) * 4;
    const float gi = epi[(nl + 0) * 65 + mloc];
    const float gf = epi[(nl + 1) * 65 + mloc];
    const float gg = epi[(nl + 2) * 65 + mloc];
    const float go = epi[(nl + 3) * 65 + mloc];
    const float cc = (jj == 0) ? cold.x : (jj == 1) ? cold.y : (jj == 2) ? cold.z : cold.w;
    const float cnew = sigf(gf) * cc + sigf(gi) * tanhfast(gg);
    cn[jj] = cnew;
    hn[jj] = sigf(go) * tanhfast(cnew);
  }
  *(float4*)(cst + (size_t)(m0 + mloc) * HIDDEN + (j0 + jl4)) =
      make_float4(cn[0], cn[1], cn[2], cn[3]);
  ushort4 uh, ul;
  uh.x = bf16_rne(hn[0]); uh.y = bf16_rne(hn[1]);
  uh.z = bf16_rne(hn[2]); uh.w = bf16_rne(hn[3]);
  ul.x = bf16_rne(hn[0] - bf16f(uh.x));
  ul.y = bf16_rne(hn[1] - bf16f(uh.y));
  ul.z = bf16_rne(hn[2] - bf16f(uh.z));
  ul.w = bf16_rne(hn[3] - bf16f(uh.w));
  *(ushort4*)(h_hi_w + (size_t)(m0 + mloc) * HIDDEN + (j0 + jl4)) = uh;
  *(ushort4*)(h_lo_w + (size_t)(m0 + mloc) * HIDDEN + (j0 + jl4)) = ul;
}

// ---------------- head GEMM: z = h @ W1^T + b1 (64x64 LDS pipelined, 3-MFMA) ----------------
__global__ __launch_bounds__(256) void head_gemm(
    const unsigned short* __restrict__ Ah_,     // h_hi [256][1024]
    const unsigned short* __restrict__ Al_,
    const unsigned short* __restrict__ Bh_,     // W1 hi [1024][1024]
    const unsigned short* __restrict__ Bl_,
    const float* __restrict__ bias,
    float* __restrict__ C)                      // z [256][1024]
{
  __shared__ short sb[2 * 4 * 2560];

  const int t    = threadIdx.x;
  const int lane = t & 63;
  const int wave = t >> 6;
  const int wm   = (wave >> 1) * 32;
  const int wn   = (wave & 1) * 32;
  const int col  = lane & 15;
  const int quad = lane >> 4;
  const int r    = t >> 2;
  const int k8   = (t & 3) * 8;
  const int m0   = blockIdx.y * 64;
  const int n0   = blockIdx.x * 64;

#define LOAD_TILE(kt, AH, AL, BH, BL) do {                                   \
    const int ka = (kt) * 32 + k8;                                           \
    AH = *(const uint4*)(Ah_ + (size_t)(m0 + r) * KH + ka);                  \
    AL = *(const uint4*)(Al_ + (size_t)(m0 + r) * KH + ka);                  \
    BH = *(const uint4*)(Bh_ + (size_t)(n0 + r) * KH + ka);                  \
    BL = *(const uint4*)(Bl_ + (size_t)(n0 + r) * KH + ka);                  \
  } while (0)

#define STORE_TILE(base, AH, AL, BH, BL) do {                                \
    *(uint4*)((base) +        r * 40 + k8) = AH;                             \
    *(uint4*)((base) + 2560 + r * 40 + k8) = AL;                             \
    *(uint4*)((base) + 5120 + r * 40 + k8) = BH;                             \
    *(uint4*)((base) + 7680 + r * 40 + k8) = BL;                             \
  } while (0)

  floatx4 acc[2][2];
#pragma unroll
  for (int i = 0; i < 2; ++i)
#pragma unroll
    for (int jj = 0; jj < 2; ++jj)
      acc[i][jj] = (floatx4){0.f, 0.f, 0.f, 0.f};

  uint4 cAh, cAl, cBh, cBl, nAh, nAl, nBh, nBl, tAh, tAl, tBh, tBl;
  LOAD_TILE(0, tAh, tAl, tBh, tBl);
  LOAD_TILE(1, cAh, cAl, cBh, cBl);
  STORE_TILE(sb, tAh, tAl, tBh, tBl);

  for (int kt = 0; kt < NKTH; ++kt) {
    if (kt + 2 < NKTH) LOAD_TILE(kt + 2, nAh, nAl, nBh, nBl);
    __syncthreads();
    short* bufp = sb + (kt & 1) * 10240;

    short8 ah[2], al[2], bh[2], bl[2];
#pragma unroll
    for (int mt = 0; mt < 2; ++mt) {
      const int row = (wm + mt * 16 + col) * 40 + quad * 8;
      ah[mt] = *(const short8*)(bufp + row);
      al[mt] = *(const short8*)(bufp + 2560 + row);
    }
#pragma unroll
    for (int nt = 0; nt < 2; ++nt) {
      const int row = (wn + nt * 16 + col) * 40 + quad * 8;
      bh[nt] = *(const short8*)(bufp + 5120 + row);
      bl[nt] = *(const short8*)(bufp + 7680 + row);
    }
#pragma unroll
    for (int mt = 0; mt < 2; ++mt)
#pragma unroll
      for (int nt = 0; nt < 2; ++nt)
        mfma3(acc[mt][nt], ah[mt], al[mt], bh[nt], bl[nt]);

    if (kt + 1 < NKTH) STORE_TILE(sb + ((kt + 1) & 1) * 10240, cAh, cAl, cBh, cBl);
    cAh = nAh; cAl = nAl; cBh = nBh; cBl = nBl;
  }
#undef LOAD_TILE
#undef STORE_TILE

#pragma unroll
  for (int mt = 0; mt < 2; ++mt)
#pragma unroll
    for (int nt = 0; nt < 2; ++nt) {
      const int nl = n0 + wn + nt * 16 + col;
      const float bb = bias[nl];
#pragma unroll
      for (int reg = 0; reg < 4; ++reg) {
        const int ml = m0 + wm + mt * 16 + quad * 4 + reg;
        C[(size_t)ml * LINEARN + nl] = acc[mt][nt][reg] + bb;
      }
    }
}

// ---------------- BN stats ----------------
__global__ __launch_bounds__(64) void bn_stats(
    const float* __restrict__ z, float* __restrict__ mean, float* __restrict__ rstd)
{
  const int n = blockIdx.x;
  const int t = threadIdx.x;
  float s = 0.f, s2 = 0.f;
  for (int r = t; r < BATCH; r += 64) {
    const float v = z[(size_t)r * LINEARN + n];
    s += v; s2 += v * v;
  }
#pragma unroll
  for (int off = 32; off > 0; off >>= 1) {
    s  += __shfl_down(s,  off, 64);
    s2 += __shfl_down(s2, off, 64);
  }
  if (t == 0) {
    const float mm = s * (1.f / BATCH);
    mean[n] = mm;
    rstd[n] = rsqrtf(s2 * (1.f / BATCH) - mm * mm + 1e-5f);
  }
}

// ---------------- head out ----------------
__global__ __launch_bounds__(256) void head_out(
    const float* __restrict__ z, const float* __restrict__ mean, const float* __restrict__ rstd,
    const float* __restrict__ gamma, const float* __restrict__ beta,
    const float* __restrict__ W2, const float* __restrict__ b2, float* __restrict__ out)
{
  const int b = blockIdx.x;
  const int t = threadIdx.x;
  float acc = 0.f;
  for (int n = t; n < LINEARN; n += 256) {
    float v = (z[(size_t)b * LINEARN + n] - mean[n]) * rstd[n] * gamma[n] + beta[n];
    v = fmaxf(v, 0.f);
    acc += v * W2[n];
  }
#pragma unroll
  for (int off = 32; off > 0; off >>= 1) acc += __shfl_down(acc, off, 64);
  __shared__ float ls[4];
  if ((t & 63) == 0) ls[t >> 6] = acc;
  __syncthreads();
  if (t == 0) {
    const float tot = ls[0] + ls[1] + ls[2] + ls[3] + b2[0];
    out[b] = 3.f / (1.f + __expf(-tot));
  }
}

// ---------------- launch ----------------
extern "C" void kernel_launch(void* const* d_in, const int* in_sizes, int n_in,
                              void* d_out, int out_size, void* d_ws, size_t ws_size,
                              hipStream_t stream) {
  const float* x     = (const float*)d_in[0];
  const float* W_ih  = (const float*)d_in[1];
  const float* W_hh  = (const float*)d_in[2];
  const float* b_ih  = (const float*)d_in[3];
  const float* b_hh  = (const float*)d_in[4];
  const float* W1    = (const float*)d_in[5];
  const float* b1    = (const float*)d_in[6];
  const float* gamma = (const float*)d_in[7];
  const float* beta  = (const float*)d_in[8];
  const float* W2    = (const float*)d_in[9];
  const float* b2    = (const float*)d_in[10];
  float* out = (float*)d_out;

  char* w = (char*)d_ws;
  // zero region (contiguous 2 MB): h_hi0, h_lo0, cst
  unsigned short* h_hi0 = (unsigned short*)(w + 0);          // 512 KB
  unsigned short* h_lo0 = (unsigned short*)(w + 524288);     // 512 KB
  float*          cst   = (float*)(w + 1048576);             // 1 MB
  unsigned short* h_hi1 = (unsigned short*)(w + 2097152);
  unsigned short* h_lo1 = (unsigned short*)(w + 2621440);
  unsigned short* Wph   = (unsigned short*)(w + 3145728);    // 11,010,048 B
  float*          biasp = (float*)(w + 14155776);            // 16 KB
  unsigned short* xph   = (unsigned short*)(w + 14172160);   // 20,971,520 B
  unsigned short* xpl   = (unsigned short*)(w + 35143680);   // 20,971,520 B
  unsigned short* W1ph  = (unsigned short*)(w + 56115200);   // 2 MB
  unsigned short* W1pl  = (unsigned short*)(w + 58212352);   // 2 MB
  float*          z     = (float*)(w + 60309504);            // 1 MB
  float*          mean  = (float*)(w + 61358080);
  float*          rstd  = (float*)(w + 61362176);

  zero_ws<<<512, 256, 0, stream>>>((float4*)w, 131072);
  pack_w<<<(NG * KT + 255) / 256, 256, 0, stream>>>(W_ih, W_hh, Wph);
  pack_bias<<<NG / 256, 256, 0, stream>>>(b_ih, b_hh, biasp);
  pack_x<<<(SEQ * BATCH * KXP + 255) / 256, 256, 0, stream>>>(x, xph, xpl);
  pack_w1<<<(LINEARN * HIDDEN + 255) / 256, 256, 0, stream>>>(W1, W1ph, W1pl);

  for (int t = 0; t < SEQ; ++t) {
    const unsigned short* hr_hi = (t & 1) ? h_hi1 : h_hi0;
    const unsigned short* hr_lo = (t & 1) ? h_lo1 : h_lo0;
    unsigned short* hw_hi = (t & 1) ? h_hi0 : h_hi1;
    unsigned short* hw_lo = (t & 1) ? h_lo0 : h_lo1;
    lstm_step4<<<256, 256, 0, stream>>>(
        xph + (size_t)t * BATCH * KXP, xpl + (size_t)t * BATCH * KXP,
        hr_hi, hr_lo, Wph, biasp, cst, hw_hi, hw_lo);
  }

  // final h (t=127 odd) is in h_hi0/h_lo0
  head_gemm<<<dim3(LINEARN / 64, BATCH / 64), 256, 0, stream>>>(
      h_hi0, h_lo0, W1ph, W1pl, b1, z);
  bn_stats<<<LINEARN, 64, 0, stream>>>(z, mean, rstd);
  head_out<<<BATCH, 256, 0, stream>>>(z, mean, rstd, gamma, beta, W2, b2, out);
}

// Round 8
// 1849.929 us; speedup vs baseline: 3.0523x; 2.1171x over previous
//
#include <hip/hip_runtime.h>
#include <math.h>

// ---------------- constants ----------------
#define SEQ 128
#define BATCH 256
#define INPUT 300
#define HIDDEN 1024
#define NG 4096              // 4*HIDDEN, gate-interleaved: n' = 4*j + gate
#define KH 1024
#define KXP 320              // x K padded 300->320
#define KT 1344              // KH + KXP
#define NKT64 21             // KT/64 k-tiles (BK=64)
#define HT64 16              // KH/64 h k-tiles
#define NKTH 32              // head k-tiles (K=1024, BK=32)
#define LINEARN 1024
#define AROW 72              // LDS row stride in shorts for BK=64 tiles (64 + 8 pad)
#define TILE_SH (64 * AROW)  // shorts per array (4608)
#define BUF_SH (3 * TILE_SH) // shorts per buffer (13824)

typedef __attribute__((ext_vector_type(8))) short short8;
typedef __attribute__((ext_vector_type(4))) float floatx4;

__device__ __forceinline__ float sigf(float x)     { return 1.f / (1.f + __expf(-x)); }
__device__ __forceinline__ float tanhfast(float x) { return 2.f / (1.f + __expf(-2.f * x)) - 1.f; }

__device__ __forceinline__ unsigned short bf16_rne(float f) {
  unsigned u = __float_as_uint(f);
  u += 0x7FFFu + ((u >> 16) & 1u);
  return (unsigned short)(u >> 16);
}
__device__ __forceinline__ float bf16f(unsigned short s) {
  return __uint_as_float(((unsigned)s) << 16);
}

__device__ __forceinline__ void mfma3(floatx4& acc, short8 ah, short8 al, short8 bh, short8 bl) {
  acc = __builtin_amdgcn_mfma_f32_16x16x32_bf16(ah, bh, acc, 0, 0, 0);
  acc = __builtin_amdgcn_mfma_f32_16x16x32_bf16(ah, bl, acc, 0, 0, 0);
  acc = __builtin_amdgcn_mfma_f32_16x16x32_bf16(al, bh, acc, 0, 0, 0);
}
// W kept at bf16 (hi only); A split hi/lo corrects the h/x quantization.
__device__ __forceinline__ void mfma2(floatx4& acc, short8 ah, short8 al, short8 bh) {
  acc = __builtin_amdgcn_mfma_f32_16x16x32_bf16(ah, bh, acc, 0, 0, 0);
  acc = __builtin_amdgcn_mfma_f32_16x16x32_bf16(al, bh, acc, 0, 0, 0);
}

// ---------------- zero ----------------
__global__ __launch_bounds__(256) void zero_ws(float4* p, int n4) {
  int i = blockIdx.x * 256 + threadIdx.x;
  if (i < n4) p[i] = make_float4(0.f, 0.f, 0.f, 0.f);
}

// ---------------- weight pack: gate-interleave + pad, bf16 hi only ----------------
__global__ __launch_bounds__(256) void pack_w(
    const float* __restrict__ W_ih, const float* __restrict__ W_hh,
    unsigned short* __restrict__ Wph)
{
  int id = blockIdx.x * 256 + threadIdx.x;
  if (id >= NG * KT) return;
  int n = id / KT;
  int k = id - n * KT;
  int j = n >> 2, g = n & 3;
  int srow = g * HIDDEN + j;
  float w = 0.f;
  if (k < KH) w = W_hh[(size_t)srow * HIDDEN + k];
  else if (k - KH < INPUT) w = W_ih[(size_t)srow * INPUT + (k - KH)];
  Wph[id] = bf16_rne(w);
}

__global__ __launch_bounds__(256) void pack_bias(
    const float* __restrict__ b_ih, const float* __restrict__ b_hh,
    float* __restrict__ biasp)
{
  int n = blockIdx.x * 256 + threadIdx.x;
  if (n >= NG) return;
  int j = n >> 2, g = n & 3;
  int s = g * HIDDEN + j;
  biasp[n] = b_ih[s] + b_hh[s];
}

// ---------------- pack all x timesteps to bf16 hi/lo, padded 300->320 ----------------
__global__ __launch_bounds__(256) void pack_x(
    const float* __restrict__ x, unsigned short* __restrict__ xph,
    unsigned short* __restrict__ xpl)
{
  int id = blockIdx.x * 256 + threadIdx.x;
  if (id >= SEQ * BATCH * KXP) return;
  int row = id / KXP;
  int k = id - row * KXP;
  float v = (k < INPUT) ? x[(size_t)row * INPUT + k] : 0.f;
  unsigned short hi = bf16_rne(v);
  xph[id] = hi;
  xpl[id] = bf16_rne(v - bf16f(hi));
}

// ---------------- pack W1 (head) hi/lo ----------------
__global__ __launch_bounds__(256) void pack_w1(
    const float* __restrict__ W1, unsigned short* __restrict__ W1ph,
    unsigned short* __restrict__ W1pl)
{
  int id = blockIdx.x * 256 + threadIdx.x;
  if (id >= LINEARN * HIDDEN) return;
  float w = W1[id];
  unsigned short hi = bf16_rne(w);
  W1ph[id] = hi;
  W1pl[id] = bf16_rne(w - bf16f(hi));
}

// ---------------- fused LSTM step v5: R0 pipeline, BK=64, 8 waves ----------------
// R7 lesson: direct-from-global bodies are L3-latency-bound (L2 invalidated each
// dispatch, 1 wave/SIMD = no TLP). R0's LDS double-buffered staging is the right
// structure; its overheads are 43 barriers/step and 1 wave/SIMD. v5 keeps R0's
// pipeline EXACTLY (same staging rhythm, same MFMA k-order -> same absmax) but:
//   - BK 32->64: 21 k-tiles, 22 barriers/step (vs 43), 2x MFMA per barrier interval,
//     128B-contiguous staging rows. Occupancy unaffected (grid=256=#CUs, 1 block/CU).
//   - 512 threads / 8 waves (2/SIMD): per-wave work halves; two waves per SIMD
//     overlap each other's vmcnt/lgkmcnt stalls.
__global__ __launch_bounds__(512) void lstm_step5(
    const unsigned short* __restrict__ xp_hi,   // [256][320] this step
    const unsigned short* __restrict__ xp_lo,
    const unsigned short* __restrict__ h_hi_r,  // [256][1024]
    const unsigned short* __restrict__ h_lo_r,
    const unsigned short* __restrict__ Wph,     // [4096][1344] bf16 hi
    const float* __restrict__ biasp,            // [4096]
    float* __restrict__ cst,                    // [256][1024] fp32 cell state
    unsigned short* __restrict__ h_hi_w,
    unsigned short* __restrict__ h_lo_w)
{
  __shared__ short sb[2 * BUF_SH];   // 55296 B: dbuf x {Ah,Al,B} [64][72]
  __shared__ float epi[64 * 65];     // 16640 B (separate; total 71936 B, 1 block/CU)

  const int t    = threadIdx.x;
  const int lane = t & 63;
  const int wave = t >> 6;                    // 0..7
  const int wm   = (wave >> 2) * 32;          // {0,32}
  const int wn   = (wave & 3) * 16;           // {0,16,32,48}
  const int col  = lane & 15;
  const int quad = lane >> 4;
  const int r    = t >> 3;                    // staging row 0..63
  const int k8   = (t & 7) * 8;               // staging k offset (shorts)
  const int id     = blockIdx.x;
  const int jtile  = (id & 7) * 8 + ((id >> 3) & 7);   // XCD-local j grouping
  const int mt_    = id >> 6;
  const int m0   = mt_ * 64;
  const int n0   = jtile * 64;
  const int j0   = jtile * 16;

  // epilogue mapping (threads 0..255): rows m0+mloc, cols j0+jl4..+4
  const int mloc = t >> 2;
  const int jl4  = (t & 3) * 4;
  float4 cold;
  if (t < 256) cold = *(const float4*)(cst + (size_t)(m0 + mloc) * HIDDEN + (j0 + jl4));

#define LOAD_TILE(kt, AH, AL, BH) do {                                       \
    if ((kt) < HT64) {                                                       \
      const int ka = (kt) * 64 + k8;                                         \
      AH = *(const uint4*)(h_hi_r + (size_t)(m0 + r) * KH + ka);             \
      AL = *(const uint4*)(h_lo_r + (size_t)(m0 + r) * KH + ka);             \
    } else {                                                                 \
      const int kx = ((kt) - HT64) * 64 + k8;                                \
      AH = *(const uint4*)(xp_hi + (size_t)(m0 + r) * KXP + kx);             \
      AL = *(const uint4*)(xp_lo + (size_t)(m0 + r) * KXP + kx);             \
    }                                                                        \
    BH = *(const uint4*)(Wph + (size_t)(n0 + r) * KT + (kt) * 64 + k8);      \
  } while (0)

#define STORE_TILE(base, AH, AL, BH) do {                                    \
    *(uint4*)((base) +               r * AROW + k8) = AH;                    \
    *(uint4*)((base) + TILE_SH     + r * AROW + k8) = AL;                    \
    *(uint4*)((base) + 2 * TILE_SH + r * AROW + k8) = BH;                    \
  } while (0)

  floatx4 acc[2];
  acc[0] = (floatx4){0.f, 0.f, 0.f, 0.f};
  acc[1] = (floatx4){0.f, 0.f, 0.f, 0.f};

  uint4 cAh, cAl, cBh, nAh, nAl, nBh, tAh, tAl, tBh;
  LOAD_TILE(0, tAh, tAl, tBh);
  LOAD_TILE(1, cAh, cAl, cBh);
  STORE_TILE(sb, tAh, tAl, tBh);

  const int arow0 = (wm + col) * AROW + quad * 8;        // A frag base (mt=0)
  const int arow1 = (wm + 16 + col) * AROW + quad * 8;   // mt=1
  const int brow  = (wn + col) * AROW + quad * 8;        // B frag base

  for (int kt = 0; kt < NKT64; ++kt) {
    if (kt + 2 < NKT64) LOAD_TILE(kt + 2, nAh, nAl, nBh);
    __syncthreads();                       // publish buf[kt&1]; prior reads done
    const short* bufp = sb + (kt & 1) * BUF_SH;

    // sub-k order 0 then 1 preserves R0's k accumulation order exactly.
#pragma unroll
    for (int sub = 0; sub < 2; ++sub) {
      const int so = sub * 32;
      const short8 bh = *(const short8*)(bufp + 2 * TILE_SH + brow + so);
      const short8 a0 = *(const short8*)(bufp + arow0 + so);
      const short8 l0 = *(const short8*)(bufp + TILE_SH + arow0 + so);
      const short8 a1 = *(const short8*)(bufp + arow1 + so);
      const short8 l1 = *(const short8*)(bufp + TILE_SH + arow1 + so);
      mfma2(acc[0], a0, l0, bh);
      mfma2(acc[1], a1, l1, bh);
    }

    if (kt + 1 < NKT64) STORE_TILE(sb + ((kt + 1) & 1) * BUF_SH, cAh, cAl, cBh);
    cAh = nAh; cAl = nAl; cBh = nBh;
  }
#undef LOAD_TILE
#undef STORE_TILE

  // ---- epilogue: gates -> epi[n'][m] (+bias), fused cell update ----
  const float bb = biasp[n0 + wn + col];
#pragma unroll
  for (int mt = 0; mt < 2; ++mt) {
    const int nl = wn + col;
#pragma unroll
    for (int reg = 0; reg < 4; ++reg) {
      const int ml = wm + mt * 16 + quad * 4 + reg;
      epi[nl * 65 + ml] = acc[mt][reg] + bb;
    }
  }
  __syncthreads();

  if (t < 256) {
    float cn[4], hn[4];
#pragma unroll
    for (int jj = 0; jj < 4; ++jj) {
      const int nl = (jl4 + jj) * 4;
      const float gi = epi[(nl + 0) * 65 + mloc];
      const float gf = epi[(nl + 1) * 65 + mloc];
      const float gg = epi[(nl + 2) * 65 + mloc];
      const float go = epi[(nl + 3) * 65 + mloc];
      const float cc = (jj == 0) ? cold.x : (jj == 1) ? cold.y : (jj == 2) ? cold.z : cold.w;
      const float cnew = sigf(gf) * cc + sigf(gi) * tanhfast(gg);
      cn[jj] = cnew;
      hn[jj] = sigf(go) * tanhfast(cnew);
    }
    *(float4*)(cst + (size_t)(m0 + mloc) * HIDDEN + (j0 + jl4)) =
        make_float4(cn[0], cn[1], cn[2], cn[3]);
    ushort4 uh, ul;
    uh.x = bf16_rne(hn[0]); uh.y = bf16_rne(hn[1]);
    uh.z = bf16_rne(hn[2]); uh.w = bf16_rne(hn[3]);
    ul.x = bf16_rne(hn[0] - bf16f(uh.x));
    ul.y = bf16_rne(hn[1] - bf16f(uh.y));
    ul.z = bf16_rne(hn[2] - bf16f(uh.z));
    ul.w = bf16_rne(hn[3] - bf16f(uh.w));
    *(ushort4*)(h_hi_w + (size_t)(m0 + mloc) * HIDDEN + (j0 + jl4)) = uh;
    *(ushort4*)(h_lo_w + (size_t)(m0 + mloc) * HIDDEN + (j0 + jl4)) = ul;
  }
}

// ---------------- head GEMM: z = h @ W1^T + b1 (64x64 LDS pipelined, 3-MFMA) ----------------
__global__ __launch_bounds__(256) void head_gemm(
    const unsigned short* __restrict__ Ah_,     // h_hi [256][1024]
    const unsigned short* __restrict__ Al_,
    const unsigned short* __restrict__ Bh_,     // W1 hi [1024][1024]
    const unsigned short* __restrict__ Bl_,
    const float* __restrict__ bias,
    float* __restrict__ C)                      // z [256][1024]
{
  __shared__ short sb[2 * 4 * 2560];

  const int t    = threadIdx.x;
  const int lane = t & 63;
  const int wave = t >> 6;
  const int wm   = (wave >> 1) * 32;
  const int wn   = (wave & 1) * 32;
  const int col  = lane & 15;
  const int quad = lane >> 4;
  const int r    = t >> 2;
  const int k8   = (t & 3) * 8;
  const int m0   = blockIdx.y * 64;
  const int n0   = blockIdx.x * 64;

#define LOAD_TILE(kt, AH, AL, BH, BL) do {                                   \
    const int ka = (kt) * 32 + k8;                                           \
    AH = *(const uint4*)(Ah_ + (size_t)(m0 + r) * KH + ka);                  \
    AL = *(const uint4*)(Al_ + (size_t)(m0 + r) * KH + ka);                  \
    BH = *(const uint4*)(Bh_ + (size_t)(n0 + r) * KH + ka);                  \
    BL = *(const uint4*)(Bl_ + (size_t)(n0 + r) * KH + ka);                  \
  } while (0)

#define STORE_TILE(base, AH, AL, BH, BL) do {                                \
    *(uint4*)((base) +        r * 40 + k8) = AH;                             \
    *(uint4*)((base) + 2560 + r * 40 + k8) = AL;                             \
    *(uint4*)((base) + 5120 + r * 40 + k8) = BH;                             \
    *(uint4*)((base) + 7680 + r * 40 + k8) = BL;                             \
  } while (0)

  floatx4 acc[2][2];
#pragma unroll
  for (int i = 0; i < 2; ++i)
#pragma unroll
    for (int jj = 0; jj < 2; ++jj)
      acc[i][jj] = (floatx4){0.f, 0.f, 0.f, 0.f};

  uint4 cAh, cAl, cBh, cBl, nAh, nAl, nBh, nBl, tAh, tAl, tBh, tBl;
  LOAD_TILE(0, tAh, tAl, tBh, tBl);
  LOAD_TILE(1, cAh, cAl, cBh, cBl);
  STORE_TILE(sb, tAh, tAl, tBh, tBl);

  for (int kt = 0; kt < NKTH; ++kt) {
    if (kt + 2 < NKTH) LOAD_TILE(kt + 2, nAh, nAl, nBh, nBl);
    __syncthreads();
    short* bufp = sb + (kt & 1) * 10240;

    short8 ah[2], al[2], bh[2], bl[2];
#pragma unroll
    for (int mt = 0; mt < 2; ++mt) {
      const int row = (wm + mt * 16 + col) * 40 + quad * 8;
      ah[mt] = *(const short8*)(bufp + row);
      al[mt] = *(const short8*)(bufp + 2560 + row);
    }
#pragma unroll
    for (int nt = 0; nt < 2; ++nt) {
      const int row = (wn + nt * 16 + col) * 40 + quad * 8;
      bh[nt] = *(const short8*)(bufp + 5120 + row);
      bl[nt] = *(const short8*)(bufp + 7680 + row);
    }
#pragma unroll
    for (int mt = 0; mt < 2; ++mt)
#pragma unroll
      for (int nt = 0; nt < 2; ++nt)
        mfma3(acc[mt][nt], ah[mt], al[mt], bh[nt], bl[nt]);

    if (kt + 1 < NKTH) STORE_TILE(sb + ((kt + 1) & 1) * 10240, cAh, cAl, cBh, cBl);
    cAh = nAh; cAl = nAl; cBh = nBh; cBl = nBl;
  }
#undef LOAD_TILE
#undef STORE_TILE

#pragma unroll
  for (int mt = 0; mt < 2; ++mt)
#pragma unroll
    for (int nt = 0; nt < 2; ++nt) {
      const int nl = n0 + wn + nt * 16 + col;
      const float bb = bias[nl];
#pragma unroll
      for (int reg = 0; reg < 4; ++reg) {
        const int ml = m0 + wm + mt * 16 + quad * 4 + reg;
        C[(size_t)ml * LINEARN + nl] = acc[mt][nt][reg] + bb;
      }
    }
}

// ---------------- BN stats ----------------
__global__ __launch_bounds__(64) void bn_stats(
    const float* __restrict__ z, float* __restrict__ mean, float* __restrict__ rstd)
{
  const int n = blockIdx.x;
  const int t = threadIdx.x;
  float s = 0.f, s2 = 0.f;
  for (int r = t; r < BATCH; r += 64) {
    const float v = z[(size_t)r * LINEARN + n];
    s += v; s2 += v * v;
  }
#pragma unroll
  for (int off = 32; off > 0; off >>= 1) {
    s  += __shfl_down(s,  off, 64);
    s2 += __shfl_down(s2, off, 64);
  }
  if (t == 0) {
    const float mm = s * (1.f / BATCH);
    mean[n] = mm;
    rstd[n] = rsqrtf(s2 * (1.f / BATCH) - mm * mm + 1e-5f);
  }
}

// ---------------- head out ----------------
__global__ __launch_bounds__(256) void head_out(
    const float* __restrict__ z, const float* __restrict__ mean, const float* __restrict__ rstd,
    const float* __restrict__ gamma, const float* __restrict__ beta,
    const float* __restrict__ W2, const float* __restrict__ b2, float* __restrict__ out)
{
  const int b = blockIdx.x;
  const int t = threadIdx.x;
  float acc = 0.f;
  for (int n = t; n < LINEARN; n += 256) {
    float v = (z[(size_t)b * LINEARN + n] - mean[n]) * rstd[n] * gamma[n] + beta[n];
    v = fmaxf(v, 0.f);
    acc += v * W2[n];
  }
#pragma unroll
  for (int off = 32; off > 0; off >>= 1) acc += __shfl_down(acc, off, 64);
  __shared__ float ls[4];
  if ((t & 63) == 0) ls[t >> 6] = acc;
  __syncthreads();
  if (t == 0) {
    const float tot = ls[0] + ls[1] + ls[2] + ls[3] + b2[0];
    out[b] = 3.f / (1.f + __expf(-tot));
  }
}

// ---------------- launch ----------------
extern "C" void kernel_launch(void* const* d_in, const int* in_sizes, int n_in,
                              void* d_out, int out_size, void* d_ws, size_t ws_size,
                              hipStream_t stream) {
  const float* x     = (const float*)d_in[0];
  const float* W_ih  = (const float*)d_in[1];
  const float* W_hh  = (const float*)d_in[2];
  const float* b_ih  = (const float*)d_in[3];
  const float* b_hh  = (const float*)d_in[4];
  const float* W1    = (const float*)d_in[5];
  const float* b1    = (const float*)d_in[6];
  const float* gamma = (const float*)d_in[7];
  const float* beta  = (const float*)d_in[8];
  const float* W2    = (const float*)d_in[9];
  const float* b2    = (const float*)d_in[10];
  float* out = (float*)d_out;

  char* w = (char*)d_ws;
  // zero region (contiguous 2 MB): h_hi0, h_lo0, cst
  unsigned short* h_hi0 = (unsigned short*)(w + 0);          // 512 KB
  unsigned short* h_lo0 = (unsigned short*)(w + 524288);     // 512 KB
  float*          cst   = (float*)(w + 1048576);             // 1 MB
  unsigned short* h_hi1 = (unsigned short*)(w + 2097152);
  unsigned short* h_lo1 = (unsigned short*)(w + 2621440);
  unsigned short* Wph   = (unsigned short*)(w + 3145728);    // 11,010,048 B
  float*          biasp = (float*)(w + 14155776);            // 16 KB
  unsigned short* xph   = (unsigned short*)(w + 14172160);   // 20,971,520 B
  unsigned short* xpl   = (unsigned short*)(w + 35143680);   // 20,971,520 B
  unsigned short* W1ph  = (unsigned short*)(w + 56115200);   // 2 MB
  unsigned short* W1pl  = (unsigned short*)(w + 58212352);   // 2 MB
  float*          z     = (float*)(w + 60309504);            // 1 MB
  float*          mean  = (float*)(w + 61358080);
  float*          rstd  = (float*)(w + 61362176);

  zero_ws<<<512, 256, 0, stream>>>((float4*)w, 131072);
  pack_w<<<(NG * KT + 255) / 256, 256, 0, stream>>>(W_ih, W_hh, Wph);
  pack_bias<<<NG / 256, 256, 0, stream>>>(b_ih, b_hh, biasp);
  pack_x<<<(SEQ * BATCH * KXP + 255) / 256, 256, 0, stream>>>(x, xph, xpl);
  pack_w1<<<(LINEARN * HIDDEN + 255) / 256, 256, 0, stream>>>(W1, W1ph, W1pl);

  for (int t = 0; t < SEQ; ++t) {
    const unsigned short* hr_hi = (t & 1) ? h_hi1 : h_hi0;
    const unsigned short* hr_lo = (t & 1) ? h_lo1 : h_lo0;
    unsigned short* hw_hi = (t & 1) ? h_hi0 : h_hi1;
    unsigned short* hw_lo = (t & 1) ? h_lo0 : h_lo1;
    lstm_step5<<<256, 512, 0, stream>>>(
        xph + (size_t)t * BATCH * KXP, xpl + (size_t)t * BATCH * KXP,
        hr_hi, hr_lo, Wph, biasp, cst, hw_hi, hw_lo);
  }

  // final h (t=127 odd) is in h_hi0/h_lo0
  head_gemm<<<dim3(LINEARN / 64, BATCH / 64), 256, 0, stream>>>(
      h_hi0, h_lo0, W1ph, W1pl, b1, z);
  bn_stats<<<LINEARN, 64, 0, stream>>>(z, mean, rstd);
  head_out<<<BATCH, 256, 0, stream>>>(z, mean, rstd, gamma, beta, W2, b2, out);
}

// Round 9
// 1797.380 us; speedup vs baseline: 3.1415x; 1.0292x over previous
//
#include <hip/hip_runtime.h>
#include <math.h>

// ---------------- constants ----------------
#define SEQ 128
#define BATCH 256
#define INPUT 300
#define HIDDEN 1024
#define NG 4096              // 4*HIDDEN, gate-interleaved: n' = 4*j + gate
#define KH 1024
#define KXP 384              // x K padded 300->384 (BK=128 alignment)
#define KT 1408              // KH + KXP (padded; pad region is exact zeros)
#define NKT128 11            // KT/128 k-tiles
#define HT128 8              // KH/128 h k-tiles
#define NKTH 32              // head k-tiles (K=1024, BK=32)
#define LINEARN 1024
#define AROW 136             // LDS row stride in shorts for BK=128 tiles (128 + 8 pad)
#define TILE_SH (64 * AROW)  // shorts per array (8704)
#define BUF_SH (3 * TILE_SH) // shorts per buffer (26112)

typedef __attribute__((ext_vector_type(8))) short short8;
typedef __attribute__((ext_vector_type(4))) float floatx4;

__device__ __forceinline__ float sigf(float x)     { return 1.f / (1.f + __expf(-x)); }
__device__ __forceinline__ float tanhfast(float x) { return 2.f / (1.f + __expf(-2.f * x)) - 1.f; }

__device__ __forceinline__ unsigned short bf16_rne(float f) {
  unsigned u = __float_as_uint(f);
  u += 0x7FFFu + ((u >> 16) & 1u);
  return (unsigned short)(u >> 16);
}
__device__ __forceinline__ float bf16f(unsigned short s) {
  return __uint_as_float(((unsigned)s) << 16);
}

__device__ __forceinline__ void mfma3(floatx4& acc, short8 ah, short8 al, short8 bh, short8 bl) {
  acc = __builtin_amdgcn_mfma_f32_16x16x32_bf16(ah, bh, acc, 0, 0, 0);
  acc = __builtin_amdgcn_mfma_f32_16x16x32_bf16(ah, bl, acc, 0, 0, 0);
  acc = __builtin_amdgcn_mfma_f32_16x16x32_bf16(al, bh, acc, 0, 0, 0);
}
// W kept at bf16 (hi only); A split hi/lo corrects the h/x quantization.
__device__ __forceinline__ void mfma2(floatx4& acc, short8 ah, short8 al, short8 bh) {
  acc = __builtin_amdgcn_mfma_f32_16x16x32_bf16(ah, bh, acc, 0, 0, 0);
  acc = __builtin_amdgcn_mfma_f32_16x16x32_bf16(al, bh, acc, 0, 0, 0);
}

// ---------------- zero ----------------
__global__ __launch_bounds__(256) void zero_ws(float4* p, int n4) {
  int i = blockIdx.x * 256 + threadIdx.x;
  if (i < n4) p[i] = make_float4(0.f, 0.f, 0.f, 0.f);
}

// ---------------- weight pack: gate-interleave + pad, bf16 hi only ----------------
__global__ __launch_bounds__(256) void pack_w(
    const float* __restrict__ W_ih, const float* __restrict__ W_hh,
    unsigned short* __restrict__ Wph)
{
  int id = blockIdx.x * 256 + threadIdx.x;
  if (id >= NG * KT) return;
  int n = id / KT;
  int k = id - n * KT;
  int j = n >> 2, g = n & 3;
  int srow = g * HIDDEN + j;
  float w = 0.f;
  if (k < KH) w = W_hh[(size_t)srow * HIDDEN + k];
  else if (k - KH < INPUT) w = W_ih[(size_t)srow * INPUT + (k - KH)];
  Wph[id] = bf16_rne(w);
}

__global__ __launch_bounds__(256) void pack_bias(
    const float* __restrict__ b_ih, const float* __restrict__ b_hh,
    float* __restrict__ biasp)
{
  int n = blockIdx.x * 256 + threadIdx.x;
  if (n >= NG) return;
  int j = n >> 2, g = n & 3;
  int s = g * HIDDEN + j;
  biasp[n] = b_ih[s] + b_hh[s];
}

// ---------------- pack all x timesteps to bf16 hi/lo, padded 300->384 ----------------
__global__ __launch_bounds__(256) void pack_x(
    const float* __restrict__ x, unsigned short* __restrict__ xph,
    unsigned short* __restrict__ xpl)
{
  int id = blockIdx.x * 256 + threadIdx.x;
  if (id >= SEQ * BATCH * KXP) return;
  int row = id / KXP;
  int k = id - row * KXP;
  float v = (k < INPUT) ? x[(size_t)row * INPUT + k] : 0.f;
  unsigned short hi = bf16_rne(v);
  xph[id] = hi;
  xpl[id] = bf16_rne(v - bf16f(hi));
}

// ---------------- pack W1 (head) hi/lo ----------------
__global__ __launch_bounds__(256) void pack_w1(
    const float* __restrict__ W1, unsigned short* __restrict__ W1ph,
    unsigned short* __restrict__ W1pl)
{
  int id = blockIdx.x * 256 + threadIdx.x;
  if (id >= LINEARN * HIDDEN) return;
  float w = W1[id];
  unsigned short hi = bf16_rne(w);
  W1ph[id] = hi;
  W1pl[id] = bf16_rne(w - bf16f(hi));
}

// ---------------- fused LSTM step v6: BK=128, 8 waves, 1m x 2n fragments ----------------
// R8 WIN analysis: staged pipeline + TLP is right; remaining slack = barriers (22) and
// LDS-read volume. v6: BK 64->128 (K padded to 1408 with exact zeros -> bitwise-identical
// accumulation): 11 k-tiles, 12 barriers/step, 2x latency window. Fragment layout
// 1m x 2n per wave: 4 ds_read_b128 feed 4 v_mfma per sub-k (20% fewer LDS reads than
// 2m x 1n). MFMA k-order per output element unchanged -> same absmax.
__global__ __launch_bounds__(512) void lstm_step6(
    const unsigned short* __restrict__ xp_hi,   // [256][384] this step
    const unsigned short* __restrict__ xp_lo,
    const unsigned short* __restrict__ h_hi_r,  // [256][1024]
    const unsigned short* __restrict__ h_lo_r,
    const unsigned short* __restrict__ Wph,     // [4096][1408] bf16 hi
    const float* __restrict__ biasp,            // [4096]
    float* __restrict__ cst,                    // [256][1024] fp32 cell state
    unsigned short* __restrict__ h_hi_w,
    unsigned short* __restrict__ h_lo_w)
{
  __shared__ short sb[2 * BUF_SH];   // 104448 B: dbuf x {Ah,Al,B} [64][136]
  __shared__ float epi[64 * 65];     // 16640 B (total 121088 B, 1 block/CU)

  const int t    = threadIdx.x;
  const int lane = t & 63;
  const int wave = t >> 6;                    // 0..7
  const int wm   = (wave & 3) * 16;           // {0,16,32,48} 1 m-frag
  const int wn   = (wave >> 2) * 32;          // {0,32}       2 n-frags
  const int col  = lane & 15;
  const int quad = lane >> 4;
  const int r    = t >> 3;                    // staging row 0..63
  const int k8   = (t & 7) * 8;               // staging k offset (shorts), + second at +64
  const int id     = blockIdx.x;
  const int jtile  = (id & 7) * 8 + ((id >> 3) & 7);   // XCD-local j grouping
  const int mt_    = id >> 6;
  const int m0   = mt_ * 64;
  const int n0   = jtile * 64;
  const int j0   = jtile * 16;

  // epilogue mapping (threads 0..255): rows m0+mloc, cols j0+jl4..+4
  const int mloc = t >> 2;
  const int jl4  = (t & 3) * 4;
  float4 cold;
  if (t < 256) cold = *(const float4*)(cst + (size_t)(m0 + mloc) * HIDDEN + (j0 + jl4));

#define LOAD_TILE(kt, AH0, AH1, AL0, AL1, BH0, BH1) do {                     \
    if ((kt) < HT128) {                                                      \
      const int ka = (kt) * 128 + k8;                                        \
      AH0 = *(const uint4*)(h_hi_r + (size_t)(m0 + r) * KH + ka);            \
      AH1 = *(const uint4*)(h_hi_r + (size_t)(m0 + r) * KH + ka + 64);       \
      AL0 = *(const uint4*)(h_lo_r + (size_t)(m0 + r) * KH + ka);            \
      AL1 = *(const uint4*)(h_lo_r + (size_t)(m0 + r) * KH + ka + 64);       \
    } else {                                                                 \
      const int kx = ((kt) - HT128) * 128 + k8;                              \
      AH0 = *(const uint4*)(xp_hi + (size_t)(m0 + r) * KXP + kx);            \
      AH1 = *(const uint4*)(xp_hi + (size_t)(m0 + r) * KXP + kx + 64);       \
      AL0 = *(const uint4*)(xp_lo + (size_t)(m0 + r) * KXP + kx);            \
      AL1 = *(const uint4*)(xp_lo + (size_t)(m0 + r) * KXP + kx + 64);       \
    }                                                                        \
    BH0 = *(const uint4*)(Wph + (size_t)(n0 + r) * KT + (kt) * 128 + k8);    \
    BH1 = *(const uint4*)(Wph + (size_t)(n0 + r) * KT + (kt) * 128 + k8 + 64);\
  } while (0)

#define STORE_TILE(base, AH0, AH1, AL0, AL1, BH0, BH1) do {                  \
    *(uint4*)((base) +               r * AROW + k8)      = AH0;              \
    *(uint4*)((base) +               r * AROW + k8 + 64) = AH1;              \
    *(uint4*)((base) + TILE_SH     + r * AROW + k8)      = AL0;              \
    *(uint4*)((base) + TILE_SH     + r * AROW + k8 + 64) = AL1;              \
    *(uint4*)((base) + 2 * TILE_SH + r * AROW + k8)      = BH0;              \
    *(uint4*)((base) + 2 * TILE_SH + r * AROW + k8 + 64) = BH1;              \
  } while (0)

  floatx4 acc[2];
  acc[0] = (floatx4){0.f, 0.f, 0.f, 0.f};
  acc[1] = (floatx4){0.f, 0.f, 0.f, 0.f};

  uint4 cA0, cA1, cL0, cL1, cB0, cB1;
  uint4 nA0, nA1, nL0, nL1, nB0, nB1;
  uint4 tA0, tA1, tL0, tL1, tB0, tB1;
  LOAD_TILE(0, tA0, tA1, tL0, tL1, tB0, tB1);
  LOAD_TILE(1, cA0, cA1, cL0, cL1, cB0, cB1);
  STORE_TILE(sb, tA0, tA1, tL0, tL1, tB0, tB1);

  const int arow  = (wm + col) * AROW + quad * 8;        // A frag base
  const int brow0 = (wn + col) * AROW + quad * 8;        // B frag base (nt=0)
  const int brow1 = (wn + 16 + col) * AROW + quad * 8;   // nt=1

  for (int kt = 0; kt < NKT128; ++kt) {
    if (kt + 2 < NKT128) LOAD_TILE(kt + 2, nA0, nA1, nL0, nL1, nB0, nB1);
    __syncthreads();                       // publish buf[kt&1]; prior reads done
    const short* bufp = sb + (kt & 1) * BUF_SH;

    // sub-k ascending preserves global k accumulation order exactly.
#pragma unroll
    for (int sub = 0; sub < 4; ++sub) {
      const int so = sub * 32;
      const short8 a  = *(const short8*)(bufp + arow + so);
      const short8 l  = *(const short8*)(bufp + TILE_SH + arow + so);
      const short8 b0 = *(const short8*)(bufp + 2 * TILE_SH + brow0 + so);
      const short8 b1 = *(const short8*)(bufp + 2 * TILE_SH + brow1 + so);
      mfma2(acc[0], a, l, b0);
      mfma2(acc[1], a, l, b1);
    }

    if (kt + 1 < NKT128) STORE_TILE(sb + ((kt + 1) & 1) * BUF_SH, cA0, cA1, cL0, cL1, cB0, cB1);
    cA0 = nA0; cA1 = nA1; cL0 = nL0; cL1 = nL1; cB0 = nB0; cB1 = nB1;
  }
#undef LOAD_TILE
#undef STORE_TILE

  // ---- epilogue: gates -> epi[n'][m] (+bias), fused cell update ----
  const float bias0 = biasp[n0 + wn + col];
  const float bias1 = biasp[n0 + wn + 16 + col];
#pragma unroll
  for (int nt = 0; nt < 2; ++nt) {
    const int nl = wn + nt * 16 + col;
    const float bb = nt ? bias1 : bias0;
#pragma unroll
    for (int reg = 0; reg < 4; ++reg) {
      const int ml = wm + quad * 4 + reg;
      epi[nl * 65 + ml] = acc[nt][reg] + bb;
    }
  }
  __syncthreads();

  if (t < 256) {
    float cn[4], hn[4];
#pragma unroll
    for (int jj = 0; jj < 4; ++jj) {
      const int nl = (jl4 + jj) * 4;
      const float gi = epi[(nl + 0) * 65 + mloc];
      const float gf = epi[(nl + 1) * 65 + mloc];
      const float gg = epi[(nl + 2) * 65 + mloc];
      const float go = epi[(nl + 3) * 65 + mloc];
      const float cc = (jj == 0) ? cold.x : (jj == 1) ? cold.y : (jj == 2) ? cold.z : cold.w;
      const float cnew = sigf(gf) * cc + sigf(gi) * tanhfast(gg);
      cn[jj] = cnew;
      hn[jj] = sigf(go) * tanhfast(cnew);
    }
    *(float4*)(cst + (size_t)(m0 + mloc) * HIDDEN + (j0 + jl4)) =
        make_float4(cn[0], cn[1], cn[2], cn[3]);
    ushort4 uh, ul;
    uh.x = bf16_rne(hn[0]); uh.y = bf16_rne(hn[1]);
    uh.z = bf16_rne(hn[2]); uh.w = bf16_rne(hn[3]);
    ul.x = bf16_rne(hn[0] - bf16f(uh.x));
    ul.y = bf16_rne(hn[1] - bf16f(uh.y));
    ul.z = bf16_rne(hn[2] - bf16f(uh.z));
    ul.w = bf16_rne(hn[3] - bf16f(uh.w));
    *(ushort4*)(h_hi_w + (size_t)(m0 + mloc) * HIDDEN + (j0 + jl4)) = uh;
    *(ushort4*)(h_lo_w + (size_t)(m0 + mloc) * HIDDEN + (j0 + jl4)) = ul;
  }
}

// ---------------- head GEMM: z = h @ W1^T + b1 (64x64 LDS pipelined, 3-MFMA) ----------------
__global__ __launch_bounds__(256) void head_gemm(
    const unsigned short* __restrict__ Ah_,     // h_hi [256][1024]
    const unsigned short* __restrict__ Al_,
    const unsigned short* __restrict__ Bh_,     // W1 hi [1024][1024]
    const unsigned short* __restrict__ Bl_,
    const float* __restrict__ bias,
    float* __restrict__ C)                      // z [256][1024]
{
  __shared__ short sb[2 * 4 * 2560];

  const int t    = threadIdx.x;
  const int lane = t & 63;
  const int wave = t >> 6;
  const int wm   = (wave >> 1) * 32;
  const int wn   = (wave & 1) * 32;
  const int col  = lane & 15;
  const int quad = lane >> 4;
  const int r    = t >> 2;
  const int k8   = (t & 3) * 8;
  const int m0   = blockIdx.y * 64;
  const int n0   = blockIdx.x * 64;

#define LOAD_TILE(kt, AH, AL, BH, BL) do {                                   \
    const int ka = (kt) * 32 + k8;                                           \
    AH = *(const uint4*)(Ah_ + (size_t)(m0 + r) * KH + ka);                  \
    AL = *(const uint4*)(Al_ + (size_t)(m0 + r) * KH + ka);                  \
    BH = *(const uint4*)(Bh_ + (size_t)(n0 + r) * KH + ka);                  \
    BL = *(const uint4*)(Bl_ + (size_t)(n0 + r) * KH + ka);                  \
  } while (0)

#define STORE_TILE(base, AH, AL, BH, BL) do {                                \
    *(uint4*)((base) +        r * 40 + k8) = AH;                             \
    *(uint4*)((base) + 2560 + r * 40 + k8) = AL;                             \
    *(uint4*)((base) + 5120 + r * 40 + k8) = BH;                             \
    *(uint4*)((base) + 7680 + r * 40 + k8) = BL;                             \
  } while (0)

  floatx4 acc[2][2];
#pragma unroll
  for (int i = 0; i < 2; ++i)
#pragma unroll
    for (int jj = 0; jj < 2; ++jj)
      acc[i][jj] = (floatx4){0.f, 0.f, 0.f, 0.f};

  uint4 cAh, cAl, cBh, cBl, nAh, nAl, nBh, nBl, tAh, tAl, tBh, tBl;
  LOAD_TILE(0, tAh, tAl, tBh, tBl);
  LOAD_TILE(1, cAh, cAl, cBh, cBl);
  STORE_TILE(sb, tAh, tAl, tBh, tBl);

  for (int kt = 0; kt < NKTH; ++kt) {
    if (kt + 2 < NKTH) LOAD_TILE(kt + 2, nAh, nAl, nBh, nBl);
    __syncthreads();
    short* bufp = sb + (kt & 1) * 10240;

    short8 ah[2], al[2], bh[2], bl[2];
#pragma unroll
    for (int mt = 0; mt < 2; ++mt) {
      const int row = (wm + mt * 16 + col) * 40 + quad * 8;
      ah[mt] = *(const short8*)(bufp + row);
      al[mt] = *(const short8*)(bufp + 2560 + row);
    }
#pragma unroll
    for (int nt = 0; nt < 2; ++nt) {
      const int row = (wn + nt * 16 + col) * 40 + quad * 8;
      bh[nt] = *(const short8*)(bufp + 5120 + row);
      bl[nt] = *(const short8*)(bufp + 7680 + row);
    }
#pragma unroll
    for (int mt = 0; mt < 2; ++mt)
#pragma unroll
      for (int nt = 0; nt < 2; ++nt)
        mfma3(acc[mt][nt], ah[mt], al[mt], bh[nt], bl[nt]);

    if (kt + 1 < NKTH) STORE_TILE(sb + ((kt + 1) & 1) * 10240, cAh, cAl, cBh, cBl);
    cAh = nAh; cAl = nAl; cBh = nBh; cBl = nBl;
  }
#undef LOAD_TILE
#undef STORE_TILE

#pragma unroll
  for (int mt = 0; mt < 2; ++mt)
#pragma unroll
    for (int nt = 0; nt < 2; ++nt) {
      const int nl = n0 + wn + nt * 16 + col;
      const float bb = bias[nl];
#pragma unroll
      for (int reg = 0; reg < 4; ++reg) {
        const int ml = m0 + wm + mt * 16 + quad * 4 + reg;
        C[(size_t)ml * LINEARN + nl] = acc[mt][nt][reg] + bb;
      }
    }
}

// ---------------- BN stats ----------------
__global__ __launch_bounds__(64) void bn_stats(
    const float* __restrict__ z, float* __restrict__ mean, float* __restrict__ rstd)
{
  const int n = blockIdx.x;
  const int t = threadIdx.x;
  float s = 0.f, s2 = 0.f;
  for (int r = t; r < BATCH; r += 64) {
    const float v = z[(size_t)r * LINEARN + n];
    s += v; s2 += v * v;
  }
#pragma unroll
  for (int off = 32; off > 0; off >>= 1) {
    s  += __shfl_down(s,  off, 64);
    s2 += __shfl_down(s2, off, 64);
  }
  if (t == 0) {
    const float mm = s * (1.f / BATCH);
    mean[n] = mm;
    rstd[n] = rsqrtf(s2 * (1.f / BATCH) - mm * mm + 1e-5f);
  }
}

// ---------------- head out ----------------
__global__ __launch_bounds__(256) void head_out(
    const float* __restrict__ z, const float* __restrict__ mean, const float* __restrict__ rstd,
    const float* __restrict__ gamma, const float* __restrict__ beta,
    const float* __restrict__ W2, const float* __restrict__ b2, float* __restrict__ out)
{
  const int b = blockIdx.x;
  const int t = threadIdx.x;
  float acc = 0.f;
  for (int n = t; n < LINEARN; n += 256) {
    float v = (z[(size_t)b * LINEARN + n] - mean[n]) * rstd[n] * gamma[n] + beta[n];
    v = fmaxf(v, 0.f);
    acc += v * W2[n];
  }
#pragma unroll
  for (int off = 32; off > 0; off >>= 1) acc += __shfl_down(acc, off, 64);
  __shared__ float ls[4];
  if ((t & 63) == 0) ls[t >> 6] = acc;
  __syncthreads();
  if (t == 0) {
    const float tot = ls[0] + ls[1] + ls[2] + ls[3] + b2[0];
    out[b] = 3.f / (1.f + __expf(-tot));
  }
}

// ---------------- launch ----------------
extern "C" void kernel_launch(void* const* d_in, const int* in_sizes, int n_in,
                              void* d_out, int out_size, void* d_ws, size_t ws_size,
                              hipStream_t stream) {
  const float* x     = (const float*)d_in[0];
  const float* W_ih  = (const float*)d_in[1];
  const float* W_hh  = (const float*)d_in[2];
  const float* b_ih  = (const float*)d_in[3];
  const float* b_hh  = (const float*)d_in[4];
  const float* W1    = (const float*)d_in[5];
  const float* b1    = (const float*)d_in[6];
  const float* gamma = (const float*)d_in[7];
  const float* beta  = (const float*)d_in[8];
  const float* W2    = (const float*)d_in[9];
  const float* b2    = (const float*)d_in[10];
  float* out = (float*)d_out;

  char* w = (char*)d_ws;
  // zero region (contiguous 2 MB): h_hi0, h_lo0, cst
  unsigned short* h_hi0 = (unsigned short*)(w + 0);          // 512 KB
  unsigned short* h_lo0 = (unsigned short*)(w + 524288);     // 512 KB
  float*          cst   = (float*)(w + 1048576);             // 1 MB
  unsigned short* h_hi1 = (unsigned short*)(w + 2097152);
  unsigned short* h_lo1 = (unsigned short*)(w + 2621440);
  unsigned short* Wph   = (unsigned short*)(w + 3145728);    // 4096*1408*2 = 11,534,336
  float*          biasp = (float*)(w + 14680064);            // 16 KB
  unsigned short* xph   = (unsigned short*)(w + 14696448);   // 128*256*384*2 = 25,165,824
  unsigned short* xpl   = (unsigned short*)(w + 39862272);   // 25,165,824
  unsigned short* W1ph  = (unsigned short*)(w + 65028096);   // 2 MB
  unsigned short* W1pl  = (unsigned short*)(w + 67125248);   // 2 MB
  float*          z     = (float*)(w + 69222400);            // 1 MB
  float*          mean  = (float*)(w + 70270976);
  float*          rstd  = (float*)(w + 70275072);

  zero_ws<<<512, 256, 0, stream>>>((float4*)w, 131072);
  pack_w<<<(NG * KT + 255) / 256, 256, 0, stream>>>(W_ih, W_hh, Wph);
  pack_bias<<<NG / 256, 256, 0, stream>>>(b_ih, b_hh, biasp);
  pack_x<<<(SEQ * BATCH * KXP + 255) / 256, 256, 0, stream>>>(x, xph, xpl);
  pack_w1<<<(LINEARN * HIDDEN + 255) / 256, 256, 0, stream>>>(W1, W1ph, W1pl);

  for (int t = 0; t < SEQ; ++t) {
    const unsigned short* hr_hi = (t & 1) ? h_hi1 : h_hi0;
    const unsigned short* hr_lo = (t & 1) ? h_lo1 : h_lo0;
    unsigned short* hw_hi = (t & 1) ? h_hi0 : h_hi1;
    unsigned short* hw_lo = (t & 1) ? h_lo0 : h_lo1;
    lstm_step6<<<256, 512, 0, stream>>>(
        xph + (size_t)t * BATCH * KXP, xpl + (size_t)t * BATCH * KXP,
        hr_hi, hr_lo, Wph, biasp, cst, hw_hi, hw_lo);
  }

  // final h (t=127 odd) is in h_hi0/h_lo0
  head_gemm<<<dim3(LINEARN / 64, BATCH / 64), 256, 0, stream>>>(
      h_hi0, h_lo0, W1ph, W1pl, b1, z);
  bn_stats<<<LINEARN, 64, 0, stream>>>(z, mean, rstd);
  head_out<<<BATCH, 256, 0, stream>>>(z, mean, rstd, gamma, beta, W2, b2, out);
}